// Round 1
// baseline (471.332 us; speedup 1.0000x reference)
//
#include <hip/hip_runtime.h>

// ---------------------------------------------------------------------------
// 2-layer GCN forward (PyG GCNConv semantics) on MI355X.
//   out[d] = relu( p[d] * ( sum_{s->d} p[s]*h[s] + p[d]*h[d] ) + b ),  h = x@W
// where p[i] = 1/sqrt(deg[i]), deg = in-degree incl. self loop.
// Pipeline: deg -> dinv -> CSR(row_ptr,col) -> GEMM(scale epilogue) -> agg.
// Round 1: correctness-first. fp32 vector GEMM (no fp32 MFMA on CDNA4);
// CSR gather aggregation (no atomics in the hot loop).
// ---------------------------------------------------------------------------

__global__ __launch_bounds__(256) void init_deg(int* deg, int n) {
    int i = blockIdx.x * 256 + threadIdx.x;
    if (i < n) deg[i] = 1;  // self loop
}

__global__ __launch_bounds__(256) void count_deg(const int* __restrict__ dst,
                                                 int* __restrict__ deg, int e) {
    int i = blockIdx.x * 256 + threadIdx.x;
    if (i < e) atomicAdd(&deg[dst[i]], 1);
}

__global__ __launch_bounds__(256) void calc_dinv(const int* __restrict__ deg,
                                                 float* __restrict__ dinv, int n) {
    int i = blockIdx.x * 256 + threadIdx.x;
    if (i < n) dinv[i] = 1.0f / sqrtf((float)deg[i]);
}

// Single-block inclusive scan of (deg[i]-1) -> row_ptr / fill_pos.
__global__ __launch_bounds__(1024) void scan_rowptr(const int* __restrict__ deg,
                                                    int* __restrict__ row_ptr,
                                                    int* __restrict__ fill_pos, int n) {
    __shared__ int sdata[1024];
    __shared__ int carry;
    int t = threadIdx.x;
    if (t == 0) carry = 0;
    __syncthreads();
    for (int base = 0; base < n; base += 1024) {
        int i = base + t;
        int v = (i < n) ? (deg[i] - 1) : 0;
        sdata[t] = v;
        __syncthreads();
        #pragma unroll
        for (int ofs = 1; ofs < 1024; ofs <<= 1) {
            int add = (t >= ofs) ? sdata[t - ofs] : 0;
            __syncthreads();
            sdata[t] += add;
            __syncthreads();
        }
        int incl = sdata[t];
        if (i < n) {
            row_ptr[i + 1] = carry + incl;
            fill_pos[i]    = carry + incl - v;  // exclusive = row_ptr[i]
        }
        __syncthreads();
        if (t == 1023) carry += sdata[1023];
        __syncthreads();
    }
    if (t == 0) row_ptr[0] = 0;
}

__global__ __launch_bounds__(256) void fill_csr(const int* __restrict__ src,
                                                const int* __restrict__ dst,
                                                int* __restrict__ fill_pos,
                                                int* __restrict__ col, int e) {
    int i = blockIdx.x * 256 + threadIdx.x;
    if (i < e) {
        int p = atomicAdd(&fill_pos[dst[i]], 1);
        col[p] = src[i];
    }
}

// C[r][c] = dinv[r] * sum_k A[r][k]*B[k][c].  64x64 tile, 256 thr, 4x4/thread.
__global__ __launch_bounds__(256) void gemm_scale(const float* __restrict__ A,
                                                  const float* __restrict__ B,
                                                  const float* __restrict__ dinv,
                                                  float* __restrict__ C,
                                                  int M, int N, int K) {
    __shared__ float As[16][64];  // [k][m]
    __shared__ float Bs[16][64];  // [k][n]
    const int tid = threadIdx.x;
    const int tx = tid & 15;    // col group
    const int ty = tid >> 4;    // row group
    const int blockRow = blockIdx.y * 64;
    const int blockCol = blockIdx.x * 64;

    const int arow = tid >> 2;          // 0..63
    const int akq  = (tid & 3) << 2;    // 0,4,8,12
    const int brow = tid >> 4;          // 0..15
    const int bcq  = (tid & 15) << 2;   // 0..60

    const int ar = min(blockRow + arow, M - 1);  // clamp edge tile

    float acc[4][4] = {};

    for (int kt = 0; kt < K; kt += 16) {
        float4 av = *(const float4*)(A + (size_t)ar * K + kt + akq);
        As[akq + 0][arow] = av.x;
        As[akq + 1][arow] = av.y;
        As[akq + 2][arow] = av.z;
        As[akq + 3][arow] = av.w;
        float4 bv = *(const float4*)(B + (size_t)(kt + brow) * N + blockCol + bcq);
        *(float4*)&Bs[brow][bcq] = bv;
        __syncthreads();
        #pragma unroll
        for (int k = 0; k < 16; k++) {
            float4 af = *(const float4*)&As[k][ty << 2];
            float4 bf = *(const float4*)&Bs[k][tx << 2];
            float a_[4] = {af.x, af.y, af.z, af.w};
            float b_[4] = {bf.x, bf.y, bf.z, bf.w};
            #pragma unroll
            for (int i = 0; i < 4; i++)
                #pragma unroll
                for (int j = 0; j < 4; j++)
                    acc[i][j] = fmaf(a_[i], b_[j], acc[i][j]);
        }
        __syncthreads();
    }

    #pragma unroll
    for (int i = 0; i < 4; i++) {
        int r = blockRow + (ty << 2) + i;
        if (r < M) {
            float s = dinv[r];
            float4 o = make_float4(s * acc[i][0], s * acc[i][1],
                                   s * acc[i][2], s * acc[i][3]);
            *(float4*)(C + (size_t)r * N + blockCol + (tx << 2)) = o;
        }
    }
}

// One block per dst node: out[d][f] = relu(p[d]*(g[d][f] + sum_s g[s][f]) + b[f])
template <int F>
__global__ __launch_bounds__(256) void aggregate(const float* __restrict__ g,
                                                 const int* __restrict__ row_ptr,
                                                 const int* __restrict__ col_idx,
                                                 const float* __restrict__ dinv,
                                                 const float* __restrict__ bias,
                                                 float* __restrict__ out) {
    const int d = blockIdx.x;
    const int t = threadIdx.x;
    const int s0 = row_ptr[d], s1 = row_ptr[d + 1];
    const float pd = dinv[d];
    const size_t dbase = (size_t)d * F;

    float acc0 = g[dbase + t];                                   // self term
    float acc1 = (F == 512) ? g[dbase + t + 256] : 0.0f;
    for (int e = s0; e < s1; e++) {
        int s = col_idx[e];
        const float* gs = g + (size_t)s * F;
        acc0 += gs[t];
        if (F == 512) acc1 += gs[t + 256];
    }
    out[dbase + t] = fmaxf(fmaf(pd, acc0, bias[t]), 0.0f);
    if (F == 512)
        out[dbase + t + 256] = fmaxf(fmaf(pd, acc1, bias[t + 256]), 0.0f);
}

extern "C" void kernel_launch(void* const* d_in, const int* in_sizes, int n_in,
                              void* d_out, int out_size, void* d_ws, size_t ws_size,
                              hipStream_t stream) {
    const float* x  = (const float*)d_in[0];
    const int*   ei = (const int*)d_in[1];   // int32 (JAX x64-disabled)
    const float* W1 = (const float*)d_in[2];
    const float* b1 = (const float*)d_in[3];
    const float* W2 = (const float*)d_in[4];
    const float* b2 = (const float*)d_in[5];
    float* out = (float*)d_out;

    const int FIN = 512, FH = 512, FOUT = 256;
    const int n = in_sizes[0] / FIN;     // 20000
    const int e = in_sizes[1] / 2;       // 160000
    const int* src = ei;
    const int* dst = ei + e;

    // workspace carve-up (256B aligned)
    auto align_up = [](size_t v) { return (v + 255) & ~(size_t)255; };
    char* w = (char*)d_ws;
    int*   deg      = (int*)w;    w += align_up((size_t)n * 4);
    float* dinv     = (float*)w;  w += align_up((size_t)n * 4);
    int*   row_ptr  = (int*)w;    w += align_up((size_t)(n + 1) * 4);
    int*   fill_pos = (int*)w;    w += align_up((size_t)n * 4);
    int*   col_idx  = (int*)w;    w += align_up((size_t)e * 4);
    float* g        = (float*)w;  w += align_up((size_t)n * FH * 4);  // also reused for layer-2 g
    float* h1       = (float*)w;  w += align_up((size_t)n * FH * 4);

    const int nb_n = (n + 255) / 256;
    const int nb_e = (e + 255) / 256;

    init_deg<<<nb_n, 256, 0, stream>>>(deg, n);
    count_deg<<<nb_e, 256, 0, stream>>>(dst, deg, e);
    calc_dinv<<<nb_n, 256, 0, stream>>>(deg, dinv, n);
    scan_rowptr<<<1, 1024, 0, stream>>>(deg, row_ptr, fill_pos, n);
    fill_csr<<<nb_e, 256, 0, stream>>>(src, dst, fill_pos, col_idx, e);

    // layer 1: g = dinv .* (x @ W1); h1 = relu(dinv .* csr_sum(g) + b1)
    {
        dim3 grid(FH / 64, (n + 63) / 64);
        gemm_scale<<<grid, 256, 0, stream>>>(x, W1, dinv, g, n, FH, FIN);
        aggregate<512><<<n, 256, 0, stream>>>(g, row_ptr, col_idx, dinv, b1, h1);
    }
    // layer 2: g2 = dinv .* (h1 @ W2); out = relu(dinv .* csr_sum(g2) + b2)
    {
        dim3 grid(FOUT / 64, (n + 63) / 64);
        gemm_scale<<<grid, 256, 0, stream>>>(h1, W2, dinv, g, n, FOUT, FH);
        aggregate<256><<<n, 256, 0, stream>>>(g, row_ptr, col_idx, dinv, b2, out);
    }
    (void)ws_size; (void)n_in; (void)out_size;
}

// Round 2
// 277.986 us; speedup vs baseline: 1.6955x; 1.6955x over previous
//
#include <hip/hip_runtime.h>

// ---------------------------------------------------------------------------
// 2-layer GCN forward (PyG GCNConv) on MI355X, round 2: bf16 MFMA GEMMs.
//   out[d] = relu( p[d]*( sum_{s->d} p[s]*h[s] + p[d]*h[d] ) + b ),  h = x@W
// GEMM: C = dinv[r] * (A_bf16 @ W_bf16), 128x128 tile, mfma_f32_16x16x32_bf16,
// global_load_lds width=16, XOR-swizzled LDS (2-way bank aliasing = free).
// W pre-transposed to [N][K] so B-frags load like A-frags (ds_read_b128).
// CSR ranges via per-block scan + one atomic (no ordered prefix needed).
// ---------------------------------------------------------------------------

typedef __bf16 bf16x8 __attribute__((ext_vector_type(8)));
typedef float floatx4 __attribute__((ext_vector_type(4)));
typedef unsigned short ushort_t;

__device__ inline ushort_t f2bf(float f) {  // RNE fp32 -> bf16 bits
    unsigned u = __builtin_bit_cast(unsigned, f);
    unsigned r = (u + 0x7FFFu + ((u >> 16) & 1u)) >> 16;
    return (ushort_t)r;
}

__global__ __launch_bounds__(256) void init_deg(int* deg, int* counter, int n) {
    int i = blockIdx.x * 256 + threadIdx.x;
    if (i < n) deg[i] = 1;  // self loop
    if (blockIdx.x == 0 && threadIdx.x == 0) *counter = 0;
}

__global__ __launch_bounds__(256) void count_deg(const int* __restrict__ dst,
                                                 int* __restrict__ deg, int e) {
    int i = blockIdx.x * 256 + threadIdx.x;
    if (i < e) atomicAdd(&deg[dst[i]], 1);
}

__global__ __launch_bounds__(256) void calc_dinv(const int* __restrict__ deg,
                                                 float* __restrict__ dinv, int n) {
    int i = blockIdx.x * 256 + threadIdx.x;
    if (i < n) dinv[i] = 1.0f / sqrtf((float)deg[i]);
}

// Disjoint CSR ranges: per-block scan + one global atomic (order irrelevant).
__global__ __launch_bounds__(256) void assign_ranges(const int* __restrict__ deg,
                                                     int* counter,
                                                     int* __restrict__ row_start,
                                                     int* __restrict__ fill_pos, int n) {
    __shared__ int sd[256];
    __shared__ int sbase;
    int t = threadIdx.x;
    int i = blockIdx.x * 256 + t;
    int v = (i < n) ? deg[i] - 1 : 0;
    sd[t] = v;
    __syncthreads();
    for (int o = 1; o < 256; o <<= 1) {
        int a = (t >= o) ? sd[t - o] : 0;
        __syncthreads();
        sd[t] += a;
        __syncthreads();
    }
    if (t == 255) sbase = atomicAdd(counter, sd[255]);
    __syncthreads();
    if (i < n) {
        int s = sbase + sd[t] - v;  // exclusive
        row_start[i] = s;
        fill_pos[i] = s;
    }
}

__global__ __launch_bounds__(256) void fill_csr(const int* __restrict__ src,
                                                const int* __restrict__ dst,
                                                int* __restrict__ fill_pos,
                                                int* __restrict__ col, int e) {
    int i = blockIdx.x * 256 + threadIdx.x;
    if (i < e) {
        int p = atomicAdd(&fill_pos[dst[i]], 1);
        col[p] = src[i];
    }
}

__global__ __launch_bounds__(256) void convert_bf16(const float* __restrict__ in,
                                                    ushort_t* __restrict__ out, long total) {
    long i = ((long)blockIdx.x * 256 + threadIdx.x) * 4;
    if (i < total) {  // total multiple of 4
        float4 v = *(const float4*)(in + i);
        ushort4 o = make_ushort4(f2bf(v.x), f2bf(v.y), f2bf(v.z), f2bf(v.w));
        *(ushort4*)(out + i) = o;
    }
}

// in: [K][N] fp32 row-major  ->  out: [N][K] bf16 row-major
__global__ __launch_bounds__(256) void transpose_bf16(const float* __restrict__ in,
                                                      ushort_t* __restrict__ out,
                                                      int K, int N) {
    __shared__ ushort_t tile[32][33];
    int k0 = blockIdx.y * 32, n0 = blockIdx.x * 32;
    int tx = threadIdx.x & 31, ty = threadIdx.x >> 5;  // ty 0..7
    for (int r = ty; r < 32; r += 8)
        tile[r][tx] = f2bf(in[(size_t)(k0 + r) * N + n0 + tx]);
    __syncthreads();
    for (int r = ty; r < 32; r += 8)
        out[(size_t)(n0 + r) * K + k0 + tx] = tile[tx][r];
}

// C[r][c] = dinv[r] * sum_k A[r][k]*BT[c][k].  A:[M][K] bf16, BT:[N][K] bf16.
// 128x128 block tile, 4 waves (2x2 of 64x64), 4x4 frags of 16x16x32 per wave.
__global__ __launch_bounds__(256) void gemm_mfma(const ushort_t* __restrict__ A,
                                                 const ushort_t* __restrict__ BT,
                                                 const float* __restrict__ dinv,
                                                 float* __restrict__ C,
                                                 int M, int N, int K) {
    __shared__ __align__(16) ushort_t As[4096];  // 128 rows x 32 k (swizzled granules)
    __shared__ __align__(16) ushort_t Bs[4096];  // 128 n-rows x 32 k
    const int tid = threadIdx.x;
    const int w = tid >> 6, lane = tid & 63;
    const int q = lane >> 4, ml = lane & 15;
    const int wm = (w >> 1) * 64, wn = (w & 1) * 64;
    const int row0 = blockIdx.y * 128, col0 = blockIdx.x * 128;

    // --- staging: chunk at region-byte-offset o holds global (r = o/64,
    // qgran = ((o/16)&3) ^ ((r>>1)&3)), i.e. k-granule qgran of row r.
    const int off0 = w * 1024 + lane * 16;   // rep 0
    const int off1 = off0 + 4096;            // rep 1
    auto srcA = [&](int off) -> const ushort_t* {
        int r = off >> 6, s = (off >> 4) & 3, qq = s ^ ((r >> 1) & 3);
        int gr = min(row0 + r, M - 1);
        return A + (size_t)gr * K + qq * 8;
    };
    auto srcB = [&](int off) -> const ushort_t* {
        int r = off >> 6, s = (off >> 4) & 3, qq = s ^ ((r >> 1) & 3);
        return BT + (size_t)(col0 + r) * K + qq * 8;
    };
    const ushort_t* ga0 = srcA(off0);
    const ushort_t* ga1 = srcA(off1);
    const ushort_t* gb0 = srcB(off0);
    const ushort_t* gb1 = srcB(off1);
    ushort_t* lA0 = As + w * 512;          // wave-uniform LDS bases (HW adds lane*16)
    ushort_t* lA1 = As + 2048 + w * 512;
    ushort_t* lB0 = Bs + w * 512;
    ushort_t* lB1 = Bs + 2048 + w * 512;

    // --- fragment read offsets (ushort index), swizzle sel = q ^ ((row>>1)&3)
    const int selA = (ml >> 1) & 3;  // row_loc = wm+i*16+ml -> (row_loc>>1)&3 == (ml>>1)&3
    int aoff[4], boff[4];
#pragma unroll
    for (int i = 0; i < 4; i++) {
        aoff[i] = (wm + i * 16 + ml) * 32 + ((q ^ selA) << 3);
        boff[i] = (wn + i * 16 + ml) * 32 + ((q ^ selA) << 3);
    }

    floatx4 acc[4][4];
#pragma unroll
    for (int i = 0; i < 4; i++)
#pragma unroll
        for (int j = 0; j < 4; j++) acc[i][j] = (floatx4)0.0f;

    for (int kt = 0; kt < K; kt += 32) {
        __builtin_amdgcn_global_load_lds(
            (const __attribute__((address_space(1))) unsigned*)ga0,
            (__attribute__((address_space(3))) unsigned*)lA0, 16, 0, 0);
        __builtin_amdgcn_global_load_lds(
            (const __attribute__((address_space(1))) unsigned*)ga1,
            (__attribute__((address_space(3))) unsigned*)lA1, 16, 0, 0);
        __builtin_amdgcn_global_load_lds(
            (const __attribute__((address_space(1))) unsigned*)gb0,
            (__attribute__((address_space(3))) unsigned*)lB0, 16, 0, 0);
        __builtin_amdgcn_global_load_lds(
            (const __attribute__((address_space(1))) unsigned*)gb1,
            (__attribute__((address_space(3))) unsigned*)lB1, 16, 0, 0);
        ga0 += 32; ga1 += 32; gb0 += 32; gb1 += 32;
        __syncthreads();  // compiler emits vmcnt(0) drain before barrier

        bf16x8 af[4], bfr[4];
#pragma unroll
        for (int i = 0; i < 4; i++) {
            af[i] = *(const bf16x8*)(As + aoff[i]);
            bfr[i] = *(const bf16x8*)(Bs + boff[i]);
        }
#pragma unroll
        for (int i = 0; i < 4; i++)
#pragma unroll
            for (int j = 0; j < 4; j++)
                acc[i][j] = __builtin_amdgcn_mfma_f32_16x16x32_bf16(af[i], bfr[j], acc[i][j], 0, 0, 0);
        __syncthreads();
    }

    // epilogue: C/D layout col=lane&15, row=q*4+reg  [m89/m91]
#pragma unroll
    for (int i = 0; i < 4; i++) {
        int rbase = row0 + wm + i * 16 + q * 4;
        float pd[4];
#pragma unroll
        for (int r = 0; r < 4; r++) pd[r] = (rbase + r < M) ? dinv[rbase + r] : 0.0f;
#pragma unroll
        for (int j = 0; j < 4; j++) {
            int gc = col0 + wn + j * 16 + ml;
#pragma unroll
            for (int r = 0; r < 4; r++) {
                int gr = rbase + r;
                if (gr < M) C[(size_t)gr * N + gc] = pd[r] * acc[i][j][r];
            }
        }
    }
}

// Layer-1 aggregate: h1 = relu(pd*(g[d]+sum g[s]) + b) -> bf16 (feeds GEMM2)
__global__ __launch_bounds__(256) void aggregate1(const float* __restrict__ g,
                                                  const int* __restrict__ row_start,
                                                  const int* __restrict__ deg,
                                                  const int* __restrict__ col_idx,
                                                  const float* __restrict__ dinv,
                                                  const float* __restrict__ bias,
                                                  ushort_t* __restrict__ out) {
    const int d = blockIdx.x, t = threadIdx.x;
    const int s0 = row_start[d], cnt = deg[d] - 1;
    const float pd = dinv[d];
    const size_t base = (size_t)d * 512 + t * 2;
    float2 acc = *(const float2*)(g + base);  // self term
    for (int e = 0; e < cnt; e++) {
        int s = col_idx[s0 + e];
        float2 v = *(const float2*)(g + (size_t)s * 512 + t * 2);
        acc.x += v.x; acc.y += v.y;
    }
    float2 b = *(const float2*)(bias + t * 2);
    float o0 = fmaxf(fmaf(pd, acc.x, b.x), 0.0f);
    float o1 = fmaxf(fmaf(pd, acc.y, b.y), 0.0f);
    *(ushort2*)(out + base) = make_ushort2(f2bf(o0), f2bf(o1));
}

// Layer-2 aggregate: out = relu(pd*(g[d]+sum g[s]) + b) -> fp32 (final)
__global__ __launch_bounds__(256) void aggregate2(const float* __restrict__ g,
                                                  const int* __restrict__ row_start,
                                                  const int* __restrict__ deg,
                                                  const int* __restrict__ col_idx,
                                                  const float* __restrict__ dinv,
                                                  const float* __restrict__ bias,
                                                  float* __restrict__ out) {
    const int d = blockIdx.x, t = threadIdx.x;
    const int s0 = row_start[d], cnt = deg[d] - 1;
    const float pd = dinv[d];
    const size_t base = (size_t)d * 256 + t;
    float acc = g[base];  // self term
    for (int e = 0; e < cnt; e++) {
        int s = col_idx[s0 + e];
        acc += g[(size_t)s * 256 + t];
    }
    out[base] = fmaxf(fmaf(pd, acc, bias[t]), 0.0f);
}

extern "C" void kernel_launch(void* const* d_in, const int* in_sizes, int n_in,
                              void* d_out, int out_size, void* d_ws, size_t ws_size,
                              hipStream_t stream) {
    const float* x  = (const float*)d_in[0];
    const int*   ei = (const int*)d_in[1];   // int32 on device
    const float* W1 = (const float*)d_in[2];
    const float* b1 = (const float*)d_in[3];
    const float* W2 = (const float*)d_in[4];
    const float* b2 = (const float*)d_in[5];
    float* out = (float*)d_out;

    const int FIN = 512, FH = 512, FOUT = 256;
    const int n = in_sizes[0] / FIN;  // 20000
    const int e = in_sizes[1] / 2;    // 160000
    const int* src = ei;
    const int* dst = ei + e;

    auto align_up = [](size_t v) { return (v + 255) & ~(size_t)255; };
    char* w = (char*)d_ws;
    int*      deg       = (int*)w;      w += align_up((size_t)n * 4);
    float*    dinv      = (float*)w;    w += align_up((size_t)n * 4);
    int*      row_start = (int*)w;      w += align_up((size_t)n * 4);
    int*      fill_pos  = (int*)w;      w += align_up((size_t)n * 4);
    int*      counter   = (int*)w;      w += align_up(4);
    int*      col_idx   = (int*)w;      w += align_up((size_t)e * 4);
    ushort_t* xb        = (ushort_t*)w; w += align_up((size_t)n * FIN * 2);
    ushort_t* w1t       = (ushort_t*)w; w += align_up((size_t)FH * FIN * 2);
    ushort_t* w2t       = (ushort_t*)w; w += align_up((size_t)FOUT * FH * 2);
    float*    g         = (float*)w;    w += align_up((size_t)n * FH * 4);   // gemm out (reused L2)
    ushort_t* h1b       = (ushort_t*)w; w += align_up((size_t)n * FH * 2);

    const int nb_n = (n + 255) / 256;
    const int nb_e = (e + 255) / 256;

    init_deg<<<nb_n, 256, 0, stream>>>(deg, counter, n);
    count_deg<<<nb_e, 256, 0, stream>>>(dst, deg, e);
    calc_dinv<<<nb_n, 256, 0, stream>>>(deg, dinv, n);
    assign_ranges<<<nb_n, 256, 0, stream>>>(deg, counter, row_start, fill_pos, n);
    fill_csr<<<nb_e, 256, 0, stream>>>(src, dst, fill_pos, col_idx, e);

    convert_bf16<<<(int)(((long)n * FIN / 4 + 255) / 256), 256, 0, stream>>>(x, xb, (long)n * FIN);
    transpose_bf16<<<dim3(FH / 32, FIN / 32), 256, 0, stream>>>(W1, w1t, FIN, FH);
    transpose_bf16<<<dim3(FOUT / 32, FH / 32), 256, 0, stream>>>(W2, w2t, FH, FOUT);

    const int mb = (n + 127) / 128;
    // layer 1
    gemm_mfma<<<dim3(FH / 128, mb), 256, 0, stream>>>(xb, w1t, dinv, g, n, FH, FIN);
    aggregate1<<<n, 256, 0, stream>>>(g, row_start, deg, col_idx, dinv, b1, h1b);
    // layer 2
    gemm_mfma<<<dim3(FOUT / 128, mb), 256, 0, stream>>>(h1b, w2t, dinv, g, n, FOUT, FH);
    aggregate2<<<n, 256, 0, stream>>>(g, row_start, deg, col_idx, dinv, b2, out);

    (void)ws_size; (void)n_in; (void)out_size;
}

// Round 3
// 229.981 us; speedup vs baseline: 2.0494x; 1.2087x over previous
//
#include <hip/hip_runtime.h>

// ---------------------------------------------------------------------------
// 2-layer GCN forward (PyG GCNConv) on MI355X, round 3.
//   out[d] = relu( p[d]*( sum_{s->d} p[s]*h[s] + p[d]*h[d] ) + b ),  h = x@W
// R3 changes vs R2:
//  - g (GEMM output, gathered by aggregate) stored as bf16: halves the
//    memory-bound aggregate traffic AND the GEMM C-write traffic.
//  - aggregate: per-node edge list staged in LDS; edge loop unrolled x4
//    (independent row loads -> higher MLP); fp32 accumulation kept.
//  - calc_dinv folded into assign_ranges.
// ---------------------------------------------------------------------------

typedef __bf16 bf16x8 __attribute__((ext_vector_type(8)));
typedef float floatx4 __attribute__((ext_vector_type(4)));
typedef unsigned short ushort_t;
typedef unsigned int uint_t;

__device__ inline ushort_t f2bf(float f) {  // RNE fp32 -> bf16 bits
    unsigned u = __builtin_bit_cast(unsigned, f);
    unsigned r = (u + 0x7FFFu + ((u >> 16) & 1u)) >> 16;
    return (ushort_t)r;
}
__device__ inline float bf_lo(uint_t u) { return __builtin_bit_cast(float, u << 16); }
__device__ inline float bf_hi(uint_t u) { return __builtin_bit_cast(float, u & 0xFFFF0000u); }

__global__ __launch_bounds__(256) void init_deg(int* deg, int* counter, int n) {
    int i = blockIdx.x * 256 + threadIdx.x;
    if (i < n) deg[i] = 1;  // self loop
    if (blockIdx.x == 0 && threadIdx.x == 0) *counter = 0;
}

__global__ __launch_bounds__(256) void count_deg(const int* __restrict__ dst,
                                                 int* __restrict__ deg, int e) {
    int i = blockIdx.x * 256 + threadIdx.x;
    if (i < e) atomicAdd(&deg[dst[i]], 1);
}

// Disjoint CSR ranges via per-block scan + one global atomic; also dinv.
__global__ __launch_bounds__(256) void assign_ranges(const int* __restrict__ deg,
                                                     int* counter,
                                                     int* __restrict__ row_start,
                                                     int* __restrict__ fill_pos,
                                                     float* __restrict__ dinv, int n) {
    __shared__ int sd[256];
    __shared__ int sbase;
    int t = threadIdx.x;
    int i = blockIdx.x * 256 + t;
    int dg = (i < n) ? deg[i] : 1;
    if (i < n) dinv[i] = 1.0f / sqrtf((float)dg);
    int v = dg - 1;
    sd[t] = v;
    __syncthreads();
    for (int o = 1; o < 256; o <<= 1) {
        int a = (t >= o) ? sd[t - o] : 0;
        __syncthreads();
        sd[t] += a;
        __syncthreads();
    }
    if (t == 255) sbase = atomicAdd(counter, sd[255]);
    __syncthreads();
    if (i < n) {
        int s = sbase + sd[t] - v;  // exclusive
        row_start[i] = s;
        fill_pos[i] = s;
    }
}

__global__ __launch_bounds__(256) void fill_csr(const int* __restrict__ src,
                                                const int* __restrict__ dst,
                                                int* __restrict__ fill_pos,
                                                int* __restrict__ col, int e) {
    int i = blockIdx.x * 256 + threadIdx.x;
    if (i < e) {
        int p = atomicAdd(&fill_pos[dst[i]], 1);
        col[p] = src[i];
    }
}

__global__ __launch_bounds__(256) void convert_bf16(const float* __restrict__ in,
                                                    ushort_t* __restrict__ out, long total) {
    long i = ((long)blockIdx.x * 256 + threadIdx.x) * 4;
    if (i < total) {  // total multiple of 4
        float4 v = *(const float4*)(in + i);
        ushort4 o = make_ushort4(f2bf(v.x), f2bf(v.y), f2bf(v.z), f2bf(v.w));
        *(ushort4*)(out + i) = o;
    }
}

// in: [K][N] fp32 row-major  ->  out: [N][K] bf16 row-major
__global__ __launch_bounds__(256) void transpose_bf16(const float* __restrict__ in,
                                                      ushort_t* __restrict__ out,
                                                      int K, int N) {
    __shared__ ushort_t tile[32][33];
    int k0 = blockIdx.y * 32, n0 = blockIdx.x * 32;
    int tx = threadIdx.x & 31, ty = threadIdx.x >> 5;  // ty 0..7
    for (int r = ty; r < 32; r += 8)
        tile[r][tx] = f2bf(in[(size_t)(k0 + r) * N + n0 + tx]);
    __syncthreads();
    for (int r = ty; r < 32; r += 8)
        out[(size_t)(n0 + r) * K + k0 + tx] = tile[tx][r];
}

// C[r][c] = bf16( dinv[r] * sum_k A[r][k]*BT[c][k] ).  A:[M][K], BT:[N][K] bf16.
// 128x128 block tile, 4 waves (2x2 of 64x64), 4x4 frags of 16x16x32 per wave.
__global__ __launch_bounds__(256) void gemm_mfma(const ushort_t* __restrict__ A,
                                                 const ushort_t* __restrict__ BT,
                                                 const float* __restrict__ dinv,
                                                 ushort_t* __restrict__ C,
                                                 int M, int N, int K) {
    __shared__ __align__(16) ushort_t As[4096];  // 128 rows x 32 k (swizzled granules)
    __shared__ __align__(16) ushort_t Bs[4096];  // 128 n-rows x 32 k
    const int tid = threadIdx.x;
    const int w = tid >> 6, lane = tid & 63;
    const int q = lane >> 4, ml = lane & 15;
    const int wm = (w >> 1) * 64, wn = (w & 1) * 64;
    const int row0 = blockIdx.y * 128, col0 = blockIdx.x * 128;

    // staging: chunk at region-byte-offset o holds k-granule ((o/16)&3)^((r>>1)&3) of row r=o/64
    const int off0 = w * 1024 + lane * 16;   // rep 0
    const int off1 = off0 + 4096;            // rep 1
    auto srcA = [&](int off) -> const ushort_t* {
        int r = off >> 6, s = (off >> 4) & 3, qq = s ^ ((r >> 1) & 3);
        int gr = min(row0 + r, M - 1);
        return A + (size_t)gr * K + qq * 8;
    };
    auto srcB = [&](int off) -> const ushort_t* {
        int r = off >> 6, s = (off >> 4) & 3, qq = s ^ ((r >> 1) & 3);
        return BT + (size_t)(col0 + r) * K + qq * 8;
    };
    const ushort_t* ga0 = srcA(off0);
    const ushort_t* ga1 = srcA(off1);
    const ushort_t* gb0 = srcB(off0);
    const ushort_t* gb1 = srcB(off1);
    ushort_t* lA0 = As + w * 512;          // wave-uniform LDS bases (HW adds lane*16)
    ushort_t* lA1 = As + 2048 + w * 512;
    ushort_t* lB0 = Bs + w * 512;
    ushort_t* lB1 = Bs + 2048 + w * 512;

    const int selA = (ml >> 1) & 3;
    int aoff[4], boff[4];
#pragma unroll
    for (int i = 0; i < 4; i++) {
        aoff[i] = (wm + i * 16 + ml) * 32 + ((q ^ selA) << 3);
        boff[i] = (wn + i * 16 + ml) * 32 + ((q ^ selA) << 3);
    }

    floatx4 acc[4][4];
#pragma unroll
    for (int i = 0; i < 4; i++)
#pragma unroll
        for (int j = 0; j < 4; j++) acc[i][j] = (floatx4)0.0f;

    for (int kt = 0; kt < K; kt += 32) {
        __builtin_amdgcn_global_load_lds(
            (const __attribute__((address_space(1))) unsigned*)ga0,
            (__attribute__((address_space(3))) unsigned*)lA0, 16, 0, 0);
        __builtin_amdgcn_global_load_lds(
            (const __attribute__((address_space(1))) unsigned*)ga1,
            (__attribute__((address_space(3))) unsigned*)lA1, 16, 0, 0);
        __builtin_amdgcn_global_load_lds(
            (const __attribute__((address_space(1))) unsigned*)gb0,
            (__attribute__((address_space(3))) unsigned*)lB0, 16, 0, 0);
        __builtin_amdgcn_global_load_lds(
            (const __attribute__((address_space(1))) unsigned*)gb1,
            (__attribute__((address_space(3))) unsigned*)lB1, 16, 0, 0);
        ga0 += 32; ga1 += 32; gb0 += 32; gb1 += 32;
        __syncthreads();

        bf16x8 af[4], bfr[4];
#pragma unroll
        for (int i = 0; i < 4; i++) {
            af[i] = *(const bf16x8*)(As + aoff[i]);
            bfr[i] = *(const bf16x8*)(Bs + boff[i]);
        }
#pragma unroll
        for (int i = 0; i < 4; i++)
#pragma unroll
            for (int j = 0; j < 4; j++)
                acc[i][j] = __builtin_amdgcn_mfma_f32_16x16x32_bf16(af[i], bfr[j], acc[i][j], 0, 0, 0);
        __syncthreads();
    }

    // epilogue: C/D layout col=lane&15, row=q*4+reg  [m89/m91]; store bf16
#pragma unroll
    for (int i = 0; i < 4; i++) {
        int rbase = row0 + wm + i * 16 + q * 4;
        float pd[4];
#pragma unroll
        for (int r = 0; r < 4; r++) pd[r] = (rbase + r < M) ? dinv[rbase + r] : 0.0f;
#pragma unroll
        for (int j = 0; j < 4; j++) {
            int gc = col0 + wn + j * 16 + ml;
#pragma unroll
            for (int r = 0; r < 4; r++) {
                int gr = rbase + r;
                if (gr < M) C[(size_t)gr * N + gc] = f2bf(pd[r] * acc[i][j][r]);
            }
        }
    }
}

// Layer-1 aggregate: h1 = relu(pd*(g[d]+sum g[s]) + b) -> bf16 (feeds GEMM2)
// g: [n][512] bf16, read as uint (2 feats/thread). Edge list staged in LDS.
__global__ __launch_bounds__(256) void aggregate1(const uint_t* __restrict__ g,
                                                  const int* __restrict__ row_start,
                                                  const int* __restrict__ deg,
                                                  const int* __restrict__ col_idx,
                                                  const float* __restrict__ dinv,
                                                  const float* __restrict__ bias,
                                                  uint_t* __restrict__ out) {
    __shared__ int scol[256];
    const int d = blockIdx.x, t = threadIdx.x;
    const int s0 = row_start[d], cnt = deg[d] - 1;
    const float pd = dinv[d];
    const size_t base = (size_t)d * 256 + t;  // uint units (512 bf16 = 256 uint)

    uint_t us = g[base];
    float acc0 = bf_lo(us), acc1 = bf_hi(us);  // self term

    for (int cb = 0; cb < cnt; cb += 256) {
        int chunk = min(256, cnt - cb);
        if (t < chunk) scol[t] = col_idx[s0 + cb + t];
        __syncthreads();
        int e = 0;
        for (; e + 4 <= chunk; e += 4) {
            int sA = scol[e + 0], sB = scol[e + 1], sC = scol[e + 2], sD = scol[e + 3];
            uint_t u0 = g[(size_t)sA * 256 + t];
            uint_t u1 = g[(size_t)sB * 256 + t];
            uint_t u2 = g[(size_t)sC * 256 + t];
            uint_t u3 = g[(size_t)sD * 256 + t];
            acc0 += bf_lo(u0) + bf_lo(u1) + bf_lo(u2) + bf_lo(u3);
            acc1 += bf_hi(u0) + bf_hi(u1) + bf_hi(u2) + bf_hi(u3);
        }
        for (; e < chunk; e++) {
            uint_t u = g[(size_t)scol[e] * 256 + t];
            acc0 += bf_lo(u);
            acc1 += bf_hi(u);
        }
        __syncthreads();
    }
    float2 b = *(const float2*)(bias + t * 2);
    float o0 = fmaxf(fmaf(pd, acc0, b.x), 0.0f);
    float o1 = fmaxf(fmaf(pd, acc1, b.y), 0.0f);
    out[base] = (uint_t)f2bf(o0) | ((uint_t)f2bf(o1) << 16);
}

// Layer-2 aggregate: out = relu(pd*(g[d]+sum g[s]) + b) -> fp32 (final)
// g: [n][256] bf16 read as uint; 128 threads/block, 2 feats/thread.
__global__ __launch_bounds__(128) void aggregate2(const uint_t* __restrict__ g,
                                                  const int* __restrict__ row_start,
                                                  const int* __restrict__ deg,
                                                  const int* __restrict__ col_idx,
                                                  const float* __restrict__ dinv,
                                                  const float* __restrict__ bias,
                                                  float* __restrict__ out) {
    const int d = blockIdx.x, t = threadIdx.x;
    const int s0 = row_start[d], cnt = deg[d] - 1;
    const float pd = dinv[d];
    const size_t base = (size_t)d * 128 + t;  // uint units (256 bf16 = 128 uint)

    uint_t us = g[base];
    float acc0 = bf_lo(us), acc1 = bf_hi(us);  // self term

    int e = 0;
    for (; e + 4 <= cnt; e += 4) {
        int sA = col_idx[s0 + e + 0], sB = col_idx[s0 + e + 1];
        int sC = col_idx[s0 + e + 2], sD = col_idx[s0 + e + 3];
        uint_t u0 = g[(size_t)sA * 128 + t];
        uint_t u1 = g[(size_t)sB * 128 + t];
        uint_t u2 = g[(size_t)sC * 128 + t];
        uint_t u3 = g[(size_t)sD * 128 + t];
        acc0 += bf_lo(u0) + bf_lo(u1) + bf_lo(u2) + bf_lo(u3);
        acc1 += bf_hi(u0) + bf_hi(u1) + bf_hi(u2) + bf_hi(u3);
    }
    for (; e < cnt; e++) {
        uint_t u = g[(size_t)col_idx[s0 + e] * 128 + t];
        acc0 += bf_lo(u);
        acc1 += bf_hi(u);
    }
    float2 b = *(const float2*)(bias + t * 2);
    float2 o;
    o.x = fmaxf(fmaf(pd, acc0, b.x), 0.0f);
    o.y = fmaxf(fmaf(pd, acc1, b.y), 0.0f);
    *(float2*)(out + (size_t)d * 256 + t * 2) = o;
}

extern "C" void kernel_launch(void* const* d_in, const int* in_sizes, int n_in,
                              void* d_out, int out_size, void* d_ws, size_t ws_size,
                              hipStream_t stream) {
    const float* x  = (const float*)d_in[0];
    const int*   ei = (const int*)d_in[1];   // int32 on device
    const float* W1 = (const float*)d_in[2];
    const float* b1 = (const float*)d_in[3];
    const float* W2 = (const float*)d_in[4];
    const float* b2 = (const float*)d_in[5];
    float* out = (float*)d_out;

    const int FIN = 512, FH = 512, FOUT = 256;
    const int n = in_sizes[0] / FIN;  // 20000
    const int e = in_sizes[1] / 2;    // 160000
    const int* src = ei;
    const int* dst = ei + e;

    auto align_up = [](size_t v) { return (v + 255) & ~(size_t)255; };
    char* w = (char*)d_ws;
    int*      deg       = (int*)w;      w += align_up((size_t)n * 4);
    float*    dinv      = (float*)w;    w += align_up((size_t)n * 4);
    int*      row_start = (int*)w;      w += align_up((size_t)n * 4);
    int*      fill_pos  = (int*)w;      w += align_up((size_t)n * 4);
    int*      counter   = (int*)w;      w += align_up(4);
    int*      col_idx   = (int*)w;      w += align_up((size_t)e * 4);
    ushort_t* xb        = (ushort_t*)w; w += align_up((size_t)n * FIN * 2);
    ushort_t* w1t       = (ushort_t*)w; w += align_up((size_t)FH * FIN * 2);
    ushort_t* w2t       = (ushort_t*)w; w += align_up((size_t)FOUT * FH * 2);
    ushort_t* g         = (ushort_t*)w; w += align_up((size_t)n * FH * 2);  // bf16, reused L2
    ushort_t* h1b       = (ushort_t*)w; w += align_up((size_t)n * FH * 2);

    const int nb_n = (n + 255) / 256;
    const int nb_e = (e + 255) / 256;

    init_deg<<<nb_n, 256, 0, stream>>>(deg, counter, n);
    count_deg<<<nb_e, 256, 0, stream>>>(dst, deg, e);
    assign_ranges<<<nb_n, 256, 0, stream>>>(deg, counter, row_start, fill_pos, dinv, n);
    fill_csr<<<nb_e, 256, 0, stream>>>(src, dst, fill_pos, col_idx, e);

    convert_bf16<<<(int)(((long)n * FIN / 4 + 255) / 256), 256, 0, stream>>>(x, xb, (long)n * FIN);
    transpose_bf16<<<dim3(FH / 32, FIN / 32), 256, 0, stream>>>(W1, w1t, FIN, FH);
    transpose_bf16<<<dim3(FOUT / 32, FH / 32), 256, 0, stream>>>(W2, w2t, FH, FOUT);

    const int mb = (n + 127) / 128;
    // layer 1
    gemm_mfma<<<dim3(FH / 128, mb), 256, 0, stream>>>(xb, w1t, dinv, g, n, FH, FIN);
    aggregate1<<<n, 256, 0, stream>>>((const uint_t*)g, row_start, deg, col_idx, dinv, b1, (uint_t*)h1b);
    // layer 2
    gemm_mfma<<<dim3(FOUT / 128, mb), 256, 0, stream>>>(h1b, w2t, dinv, g, n, FOUT, FH);
    aggregate2<<<n, 128, 0, stream>>>((const uint_t*)g, row_start, deg, col_idx, dinv, b2, out);

    (void)ws_size; (void)n_in; (void)out_size;
}

// Round 4
// 217.718 us; speedup vs baseline: 2.1649x; 1.0563x over previous
//
#include <hip/hip_runtime.h>

// ---------------------------------------------------------------------------
// 2-layer GCN forward (PyG GCNConv) on MI355X, round 4.
//   out[d] = relu( p[d]*( sum_{s->d} p[s]*h[s] + p[d]*h[d] ) + b ),  h = x@W
// R4 changes vs R3:
//  - aggregates: no LDS col staging (avg deg = 8 -> the 2 syncthreads were
//    pure latency); gather unrolled 8/4/1 with direct uniform col reads.
//  - launches 11 -> 8: hipMemsetAsync zeroes deg+counter; count_deg +
//    convert_bf16 + both W transposes fused into one prep dispatch.
//  - deg holds REAL edge count (self loop folded in arithmetically).
// ---------------------------------------------------------------------------

typedef __bf16 bf16x8 __attribute__((ext_vector_type(8)));
typedef float floatx4 __attribute__((ext_vector_type(4)));
typedef unsigned short ushort_t;
typedef unsigned int uint_t;

__device__ inline ushort_t f2bf(float f) {  // RNE fp32 -> bf16 bits
    unsigned u = __builtin_bit_cast(unsigned, f);
    unsigned r = (u + 0x7FFFu + ((u >> 16) & 1u)) >> 16;
    return (ushort_t)r;
}
__device__ inline float bf_lo(uint_t u) { return __builtin_bit_cast(float, u << 16); }
__device__ inline float bf_hi(uint_t u) { return __builtin_bit_cast(float, u & 0xFFFF0000u); }

// [K][N] fp32 -> [N][K] bf16, one 32x32 tile per block (256 thr)
__device__ inline void transpose_tile(const float* __restrict__ in,
                                      ushort_t* __restrict__ out,
                                      int K, int N, int k0, int n0,
                                      ushort_t (*tile)[33]) {
    int tx = threadIdx.x & 31, ty = threadIdx.x >> 5;  // ty 0..7
    for (int r = ty; r < 32; r += 8)
        tile[r][tx] = f2bf(in[(size_t)(k0 + r) * N + n0 + tx]);
    __syncthreads();
    for (int r = ty; r < 32; r += 8)
        out[(size_t)(n0 + r) * K + k0 + tx] = tile[tx][r];
}

// Fused independent preprocessing: count_deg | x->bf16 | W1^T | W2^T
__global__ __launch_bounds__(256) void prep_fused(
    const int* __restrict__ dst, int* __restrict__ deg, int e, int nb_e,
    const float* __restrict__ x, ushort_t* __restrict__ xb, long xcount, int nb_conv,
    const float* __restrict__ W1, ushort_t* __restrict__ w1t,
    const float* __restrict__ W2, ushort_t* __restrict__ w2t) {
    __shared__ ushort_t tile[32][33];
    int b = blockIdx.x;
    if (b < nb_e) {
        int i = b * 256 + threadIdx.x;
        if (i < e) atomicAdd(&deg[dst[i]], 1);
        return;
    }
    b -= nb_e;
    if (b < nb_conv) {
        long i = ((long)b * 256 + threadIdx.x) * 4;
        if (i < xcount) {
            float4 v = *(const float4*)(x + i);
            ushort4 o = make_ushort4(f2bf(v.x), f2bf(v.y), f2bf(v.z), f2bf(v.w));
            *(ushort4*)(xb + i) = o;
        }
        return;
    }
    b -= nb_conv;
    if (b < 256) {  // W1: K=512, N=512 -> 16x16 tiles
        transpose_tile(W1, w1t, 512, 512, (b >> 4) * 32, (b & 15) * 32, tile);
        return;
    }
    b -= 256;       // W2: K=512, N=256 -> 8x16 tiles
    transpose_tile(W2, w2t, 512, 256, (b >> 3) * 32, (b & 7) * 32, tile);
}

// Disjoint CSR ranges via per-block scan + one global atomic; also dinv.
// deg[i] = real in-edge count (no self loop); dinv uses deg+1.
__global__ __launch_bounds__(256) void assign_ranges(const int* __restrict__ deg,
                                                     int* counter,
                                                     int* __restrict__ row_start,
                                                     int* __restrict__ fill_pos,
                                                     float* __restrict__ dinv, int n) {
    __shared__ int sd[256];
    __shared__ int sbase;
    int t = threadIdx.x;
    int i = blockIdx.x * 256 + t;
    int v = (i < n) ? deg[i] : 0;
    if (i < n) dinv[i] = 1.0f / sqrtf((float)(v + 1));
    sd[t] = v;
    __syncthreads();
    for (int o = 1; o < 256; o <<= 1) {
        int a = (t >= o) ? sd[t - o] : 0;
        __syncthreads();
        sd[t] += a;
        __syncthreads();
    }
    if (t == 255) sbase = atomicAdd(counter, sd[255]);
    __syncthreads();
    if (i < n) {
        int s = sbase + sd[t] - v;  // exclusive
        row_start[i] = s;
        fill_pos[i] = s;
    }
}

__global__ __launch_bounds__(256) void fill_csr(const int* __restrict__ src,
                                                const int* __restrict__ dst,
                                                int* __restrict__ fill_pos,
                                                int* __restrict__ col, int e) {
    int i = blockIdx.x * 256 + threadIdx.x;
    if (i < e) {
        int p = atomicAdd(&fill_pos[dst[i]], 1);
        col[p] = src[i];
    }
}

// C[r][c] = bf16( dinv[r] * sum_k A[r][k]*BT[c][k] ).  A:[M][K], BT:[N][K] bf16.
// 128x128 block tile, 4 waves (2x2 of 64x64), 4x4 frags of 16x16x32 per wave.
__global__ __launch_bounds__(256) void gemm_mfma(const ushort_t* __restrict__ A,
                                                 const ushort_t* __restrict__ BT,
                                                 const float* __restrict__ dinv,
                                                 ushort_t* __restrict__ C,
                                                 int M, int N, int K) {
    __shared__ __align__(16) ushort_t As[4096];  // 128 rows x 32 k (swizzled granules)
    __shared__ __align__(16) ushort_t Bs[4096];  // 128 n-rows x 32 k
    const int tid = threadIdx.x;
    const int w = tid >> 6, lane = tid & 63;
    const int q = lane >> 4, ml = lane & 15;
    const int wm = (w >> 1) * 64, wn = (w & 1) * 64;
    const int row0 = blockIdx.y * 128, col0 = blockIdx.x * 128;

    // staging: chunk at region-byte-offset o holds k-granule ((o/16)&3)^((r>>1)&3) of row r=o/64
    const int off0 = w * 1024 + lane * 16;   // rep 0
    const int off1 = off0 + 4096;            // rep 1
    auto srcA = [&](int off) -> const ushort_t* {
        int r = off >> 6, s = (off >> 4) & 3, qq = s ^ ((r >> 1) & 3);
        int gr = min(row0 + r, M - 1);
        return A + (size_t)gr * K + qq * 8;
    };
    auto srcB = [&](int off) -> const ushort_t* {
        int r = off >> 6, s = (off >> 4) & 3, qq = s ^ ((r >> 1) & 3);
        return BT + (size_t)(col0 + r) * K + qq * 8;
    };
    const ushort_t* ga0 = srcA(off0);
    const ushort_t* ga1 = srcA(off1);
    const ushort_t* gb0 = srcB(off0);
    const ushort_t* gb1 = srcB(off1);
    ushort_t* lA0 = As + w * 512;          // wave-uniform LDS bases (HW adds lane*16)
    ushort_t* lA1 = As + 2048 + w * 512;
    ushort_t* lB0 = Bs + w * 512;
    ushort_t* lB1 = Bs + 2048 + w * 512;

    const int selA = (ml >> 1) & 3;
    int aoff[4], boff[4];
#pragma unroll
    for (int i = 0; i < 4; i++) {
        aoff[i] = (wm + i * 16 + ml) * 32 + ((q ^ selA) << 3);
        boff[i] = (wn + i * 16 + ml) * 32 + ((q ^ selA) << 3);
    }

    floatx4 acc[4][4];
#pragma unroll
    for (int i = 0; i < 4; i++)
#pragma unroll
        for (int j = 0; j < 4; j++) acc[i][j] = (floatx4)0.0f;

    for (int kt = 0; kt < K; kt += 32) {
        __builtin_amdgcn_global_load_lds(
            (const __attribute__((address_space(1))) unsigned*)ga0,
            (__attribute__((address_space(3))) unsigned*)lA0, 16, 0, 0);
        __builtin_amdgcn_global_load_lds(
            (const __attribute__((address_space(1))) unsigned*)ga1,
            (__attribute__((address_space(3))) unsigned*)lA1, 16, 0, 0);
        __builtin_amdgcn_global_load_lds(
            (const __attribute__((address_space(1))) unsigned*)gb0,
            (__attribute__((address_space(3))) unsigned*)lB0, 16, 0, 0);
        __builtin_amdgcn_global_load_lds(
            (const __attribute__((address_space(1))) unsigned*)gb1,
            (__attribute__((address_space(3))) unsigned*)lB1, 16, 0, 0);
        ga0 += 32; ga1 += 32; gb0 += 32; gb1 += 32;
        __syncthreads();

        bf16x8 af[4], bfr[4];
#pragma unroll
        for (int i = 0; i < 4; i++) {
            af[i] = *(const bf16x8*)(As + aoff[i]);
            bfr[i] = *(const bf16x8*)(Bs + boff[i]);
        }
#pragma unroll
        for (int i = 0; i < 4; i++)
#pragma unroll
            for (int j = 0; j < 4; j++)
                acc[i][j] = __builtin_amdgcn_mfma_f32_16x16x32_bf16(af[i], bfr[j], acc[i][j], 0, 0, 0);
        __syncthreads();
    }

    // epilogue: C/D layout col=lane&15, row=q*4+reg  [m89/m91]; store bf16
#pragma unroll
    for (int i = 0; i < 4; i++) {
        int rbase = row0 + wm + i * 16 + q * 4;
        float pd[4];
#pragma unroll
        for (int r = 0; r < 4; r++) pd[r] = (rbase + r < M) ? dinv[rbase + r] : 0.0f;
#pragma unroll
        for (int j = 0; j < 4; j++) {
            int gc = col0 + wn + j * 16 + ml;
#pragma unroll
            for (int r = 0; r < 4; r++) {
                int gr = rbase + r;
                if (gr < M) C[(size_t)gr * N + gc] = f2bf(pd[r] * acc[i][j][r]);
            }
        }
    }
}

// Layer-1 aggregate: h1 = relu(pd*(g[d]+sum g[s]) + b) -> bf16 (feeds GEMM2)
// g: [n][512] bf16 read as uint (2 feats/thread). Gather unrolled 8/4/1.
__global__ __launch_bounds__(256) void aggregate1(const uint_t* __restrict__ g,
                                                  const int* __restrict__ row_start,
                                                  const int* __restrict__ deg,
                                                  const int* __restrict__ col_idx,
                                                  const float* __restrict__ dinv,
                                                  const float* __restrict__ bias,
                                                  uint_t* __restrict__ out) {
    const int d = blockIdx.x, t = threadIdx.x;
    const int s0 = row_start[d], cnt = deg[d];
    const float pd = dinv[d];
    const size_t base = (size_t)d * 256 + t;  // uint units (512 bf16 = 256 uint)

    uint_t us = g[base];
    float acc0 = bf_lo(us), acc1 = bf_hi(us);  // self term

    int e = 0;
    for (; e + 8 <= cnt; e += 8) {
        uint_t u[8];
#pragma unroll
        for (int j = 0; j < 8; j++)
            u[j] = g[(size_t)col_idx[s0 + e + j] * 256 + t];
#pragma unroll
        for (int j = 0; j < 8; j++) { acc0 += bf_lo(u[j]); acc1 += bf_hi(u[j]); }
    }
    if (e + 4 <= cnt) {
        uint_t u[4];
#pragma unroll
        for (int j = 0; j < 4; j++)
            u[j] = g[(size_t)col_idx[s0 + e + j] * 256 + t];
#pragma unroll
        for (int j = 0; j < 4; j++) { acc0 += bf_lo(u[j]); acc1 += bf_hi(u[j]); }
        e += 4;
    }
    for (; e < cnt; e++) {
        uint_t u = g[(size_t)col_idx[s0 + e] * 256 + t];
        acc0 += bf_lo(u);
        acc1 += bf_hi(u);
    }
    float2 b = *(const float2*)(bias + t * 2);
    float o0 = fmaxf(fmaf(pd, acc0, b.x), 0.0f);
    float o1 = fmaxf(fmaf(pd, acc1, b.y), 0.0f);
    out[base] = (uint_t)f2bf(o0) | ((uint_t)f2bf(o1) << 16);
}

// Layer-2 aggregate: out = relu(pd*(g[d]+sum g[s]) + b) -> fp32 (final)
// g: [n][256] bf16 read as uint; 128 threads/block.
__global__ __launch_bounds__(128) void aggregate2(const uint_t* __restrict__ g,
                                                  const int* __restrict__ row_start,
                                                  const int* __restrict__ deg,
                                                  const int* __restrict__ col_idx,
                                                  const float* __restrict__ dinv,
                                                  const float* __restrict__ bias,
                                                  float* __restrict__ out) {
    const int d = blockIdx.x, t = threadIdx.x;
    const int s0 = row_start[d], cnt = deg[d];
    const float pd = dinv[d];
    const size_t base = (size_t)d * 128 + t;  // uint units (256 bf16 = 128 uint)

    uint_t us = g[base];
    float acc0 = bf_lo(us), acc1 = bf_hi(us);  // self term

    int e = 0;
    for (; e + 8 <= cnt; e += 8) {
        uint_t u[8];
#pragma unroll
        for (int j = 0; j < 8; j++)
            u[j] = g[(size_t)col_idx[s0 + e + j] * 128 + t];
#pragma unroll
        for (int j = 0; j < 8; j++) { acc0 += bf_lo(u[j]); acc1 += bf_hi(u[j]); }
    }
    if (e + 4 <= cnt) {
        uint_t u[4];
#pragma unroll
        for (int j = 0; j < 4; j++)
            u[j] = g[(size_t)col_idx[s0 + e + j] * 128 + t];
#pragma unroll
        for (int j = 0; j < 4; j++) { acc0 += bf_lo(u[j]); acc1 += bf_hi(u[j]); }
        e += 4;
    }
    for (; e < cnt; e++) {
        uint_t u = g[(size_t)col_idx[s0 + e] * 128 + t];
        acc0 += bf_lo(u);
        acc1 += bf_hi(u);
    }
    float2 b = *(const float2*)(bias + t * 2);
    float2 o;
    o.x = fmaxf(fmaf(pd, acc0, b.x), 0.0f);
    o.y = fmaxf(fmaf(pd, acc1, b.y), 0.0f);
    *(float2*)(out + (size_t)d * 256 + t * 2) = o;
}

extern "C" void kernel_launch(void* const* d_in, const int* in_sizes, int n_in,
                              void* d_out, int out_size, void* d_ws, size_t ws_size,
                              hipStream_t stream) {
    const float* x  = (const float*)d_in[0];
    const int*   ei = (const int*)d_in[1];   // int32 on device
    const float* W1 = (const float*)d_in[2];
    const float* b1 = (const float*)d_in[3];
    const float* W2 = (const float*)d_in[4];
    const float* b2 = (const float*)d_in[5];
    float* out = (float*)d_out;

    const int FIN = 512, FH = 512, FOUT = 256;
    const int n = in_sizes[0] / FIN;  // 20000
    const int e = in_sizes[1] / 2;    // 160000
    const int* src = ei;
    const int* dst = ei + e;

    auto align_up = [](size_t v) { return (v + 255) & ~(size_t)255; };
    char* w = (char*)d_ws;
    int*      deg       = (int*)w;                         // deg[n] + counter adjacent
    int*      counter   = deg + n;
    w += align_up((size_t)(n + 1) * 4);
    float*    dinv      = (float*)w;    w += align_up((size_t)n * 4);
    int*      row_start = (int*)w;      w += align_up((size_t)n * 4);
    int*      fill_pos  = (int*)w;      w += align_up((size_t)n * 4);
    int*      col_idx   = (int*)w;      w += align_up((size_t)e * 4);
    ushort_t* xb        = (ushort_t*)w; w += align_up((size_t)n * FIN * 2);
    ushort_t* w1t       = (ushort_t*)w; w += align_up((size_t)FH * FIN * 2);
    ushort_t* w2t       = (ushort_t*)w; w += align_up((size_t)FOUT * FH * 2);
    ushort_t* g         = (ushort_t*)w; w += align_up((size_t)n * FH * 2);  // bf16, reused L2
    ushort_t* h1b       = (ushort_t*)w; w += align_up((size_t)n * FH * 2);

    const int nb_n = (n + 255) / 256;
    const int nb_e = (e + 255) / 256;
    const long xcount = (long)n * FIN;
    const int nb_conv = (int)((xcount / 4 + 255) / 256);

    hipMemsetAsync(deg, 0, (size_t)(n + 1) * 4, stream);  // deg + counter

    prep_fused<<<nb_e + nb_conv + 256 + 128, 256, 0, stream>>>(
        dst, deg, e, nb_e, x, xb, xcount, nb_conv, W1, w1t, W2, w2t);
    assign_ranges<<<nb_n, 256, 0, stream>>>(deg, counter, row_start, fill_pos, dinv, n);
    fill_csr<<<nb_e, 256, 0, stream>>>(src, dst, fill_pos, col_idx, e);

    const int mb = (n + 127) / 128;
    // layer 1
    gemm_mfma<<<dim3(FH / 128, mb), 256, 0, stream>>>(xb, w1t, dinv, g, n, FH, FIN);
    aggregate1<<<n, 256, 0, stream>>>((const uint_t*)g, row_start, deg, col_idx, dinv, b1, (uint_t*)h1b);
    // layer 2
    gemm_mfma<<<dim3(FOUT / 128, mb), 256, 0, stream>>>(h1b, w2t, dinv, g, n, FOUT, FH);
    aggregate2<<<n, 128, 0, stream>>>((const uint_t*)g, row_start, deg, col_idx, dinv, b2, out);

    (void)ws_size; (void)n_in; (void)out_size;
}

// Round 5
// 210.881 us; speedup vs baseline: 2.2351x; 1.0324x over previous
//
#include <hip/hip_runtime.h>

// ---------------------------------------------------------------------------
// 2-layer GCN forward (PyG GCNConv) on MI355X, round 5.
//   out[d] = relu( p[d]*( sum_{s->d} p[s]*h[s] + p[d]*h[d] ) + b ),  h = x@W
// R5 changes vs R4:
//  - aggregates: col_idx (and dinv) fetched once per 8-batch via coalesced
//    load + __shfl broadcast; uint2 payloads; agg1=128thr, agg2=64thr(1 wave).
//  - assign_ranges fused as tail blocks of the GEMM1 dispatch (overlap).
//    Therefore layer-1 g is stored UNSCALED bf16; agg1 applies p_s per row
//    (fma) and p_d at the end. Layer-2 keeps dinv in GEMM2 epilogue.
//  - launches 8 -> 7 (memset, prep, gemm1+ranges, fill_csr, agg1, gemm2, agg2)
// ---------------------------------------------------------------------------

typedef __bf16 bf16x8 __attribute__((ext_vector_type(8)));
typedef float floatx4 __attribute__((ext_vector_type(4)));
typedef unsigned short ushort_t;
typedef unsigned int uint_t;

__device__ inline ushort_t f2bf(float f) {  // RNE fp32 -> bf16 bits
    unsigned u = __builtin_bit_cast(unsigned, f);
    unsigned r = (u + 0x7FFFu + ((u >> 16) & 1u)) >> 16;
    return (ushort_t)r;
}
__device__ inline float bf_lo(uint_t u) { return __builtin_bit_cast(float, u << 16); }
__device__ inline float bf_hi(uint_t u) { return __builtin_bit_cast(float, u & 0xFFFF0000u); }

// [K][N] fp32 -> [N][K] bf16, one 32x32 tile per block (256 thr)
__device__ inline void transpose_tile(const float* __restrict__ in,
                                      ushort_t* __restrict__ out,
                                      int K, int N, int k0, int n0,
                                      ushort_t (*tile)[33]) {
    int tx = threadIdx.x & 31, ty = threadIdx.x >> 5;  // ty 0..7
    for (int r = ty; r < 32; r += 8)
        tile[r][tx] = f2bf(in[(size_t)(k0 + r) * N + n0 + tx]);
    __syncthreads();
    for (int r = ty; r < 32; r += 8)
        out[(size_t)(n0 + r) * K + k0 + tx] = tile[tx][r];
}

// Fused independent preprocessing: count_deg | x->bf16 | W1^T | W2^T
__global__ __launch_bounds__(256) void prep_fused(
    const int* __restrict__ dst, int* __restrict__ deg, int e, int nb_e,
    const float* __restrict__ x, ushort_t* __restrict__ xb, long xcount, int nb_conv,
    const float* __restrict__ W1, ushort_t* __restrict__ w1t,
    const float* __restrict__ W2, ushort_t* __restrict__ w2t) {
    __shared__ ushort_t tile[32][33];
    int b = blockIdx.x;
    if (b < nb_e) {
        int i = b * 256 + threadIdx.x;
        if (i < e) atomicAdd(&deg[dst[i]], 1);
        return;
    }
    b -= nb_e;
    if (b < nb_conv) {
        long i = ((long)b * 256 + threadIdx.x) * 4;
        if (i < xcount) {
            float4 v = *(const float4*)(x + i);
            ushort4 o = make_ushort4(f2bf(v.x), f2bf(v.y), f2bf(v.z), f2bf(v.w));
            *(ushort4*)(xb + i) = o;
        }
        return;
    }
    b -= nb_conv;
    if (b < 256) {  // W1: K=512, N=512 -> 16x16 tiles
        transpose_tile(W1, w1t, 512, 512, (b >> 4) * 32, (b & 15) * 32, tile);
        return;
    }
    b -= 256;       // W2: K=512, N=256 -> 8x16 tiles
    transpose_tile(W2, w2t, 512, 256, (b >> 3) * 32, (b & 7) * 32, tile);
}

__global__ __launch_bounds__(256) void fill_csr(const int* __restrict__ src,
                                                const int* __restrict__ dst,
                                                int* __restrict__ fill_pos,
                                                int* __restrict__ col, int e) {
    int i = blockIdx.x * 256 + threadIdx.x;
    if (i < e) {
        int p = atomicAdd(&fill_pos[dst[i]], 1);
        col[p] = src[i];
    }
}

// GEMM (+ optional fused assign_ranges tail blocks).
// C[r][c] = bf16( (scale?dinv[r]:1) * sum_k A[r][k]*BT[c][k] )
// A:[M][K], BT:[N][K] bf16. 128x128 tile, 4 waves, 4x4 frags of 16x16x32.
// Tail blocks (blockIdx.x >= gemm_blocks) run the CSR range scan instead
// (deg -> row_start/fill_pos/dinv_out); safe because no gemm block in THIS
// dispatch reads dinv, and consumers launch after the dispatch completes.
__global__ __launch_bounds__(256) void gemm_mfma(
    const ushort_t* __restrict__ A, const ushort_t* __restrict__ BT,
    const float* __restrict__ dinv, ushort_t* __restrict__ C,
    int M, int N, int K, int nbx, int gemm_blocks, int scale,
    const int* __restrict__ deg, int* counter, int* __restrict__ row_start,
    int* __restrict__ fill_pos, float* __restrict__ dinv_out, int n) {
    __shared__ __align__(16) ushort_t As[4096];
    __shared__ __align__(16) ushort_t Bs[4096];
    __shared__ int sd[256];
    __shared__ int sbase;

    if ((int)blockIdx.x >= gemm_blocks) {  // ---- assign_ranges path ----
        int t = threadIdx.x;
        int i = ((int)blockIdx.x - gemm_blocks) * 256 + t;
        int v = (i < n) ? deg[i] : 0;
        if (i < n) dinv_out[i] = 1.0f / sqrtf((float)(v + 1));
        sd[t] = v;
        __syncthreads();
        for (int o = 1; o < 256; o <<= 1) {
            int a = (t >= o) ? sd[t - o] : 0;
            __syncthreads();
            sd[t] += a;
            __syncthreads();
        }
        if (t == 255) sbase = atomicAdd(counter, sd[255]);
        __syncthreads();
        if (i < n) {
            int s = sbase + sd[t] - v;  // exclusive
            row_start[i] = s;
            fill_pos[i] = s;
        }
        return;
    }

    const int bx = (int)blockIdx.x % nbx, by = (int)blockIdx.x / nbx;
    const int tid = threadIdx.x;
    const int w = tid >> 6, lane = tid & 63;
    const int q = lane >> 4, ml = lane & 15;
    const int wm = (w >> 1) * 64, wn = (w & 1) * 64;
    const int row0 = by * 128, col0 = bx * 128;

    // staging: chunk at region-byte-offset o holds k-granule ((o/16)&3)^((r>>1)&3) of row r=o/64
    const int off0 = w * 1024 + lane * 16;   // rep 0
    const int off1 = off0 + 4096;            // rep 1
    auto srcA = [&](int off) -> const ushort_t* {
        int r = off >> 6, s = (off >> 4) & 3, qq = s ^ ((r >> 1) & 3);
        int gr = min(row0 + r, M - 1);
        return A + (size_t)gr * K + qq * 8;
    };
    auto srcB = [&](int off) -> const ushort_t* {
        int r = off >> 6, s = (off >> 4) & 3, qq = s ^ ((r >> 1) & 3);
        return BT + (size_t)(col0 + r) * K + qq * 8;
    };
    const ushort_t* ga0 = srcA(off0);
    const ushort_t* ga1 = srcA(off1);
    const ushort_t* gb0 = srcB(off0);
    const ushort_t* gb1 = srcB(off1);
    ushort_t* lA0 = As + w * 512;          // wave-uniform LDS bases (HW adds lane*16)
    ushort_t* lA1 = As + 2048 + w * 512;
    ushort_t* lB0 = Bs + w * 512;
    ushort_t* lB1 = Bs + 2048 + w * 512;

    const int selA = (ml >> 1) & 3;
    int aoff[4], boff[4];
#pragma unroll
    for (int i = 0; i < 4; i++) {
        aoff[i] = (wm + i * 16 + ml) * 32 + ((q ^ selA) << 3);
        boff[i] = (wn + i * 16 + ml) * 32 + ((q ^ selA) << 3);
    }

    floatx4 acc[4][4];
#pragma unroll
    for (int i = 0; i < 4; i++)
#pragma unroll
        for (int j = 0; j < 4; j++) acc[i][j] = (floatx4)0.0f;

    for (int kt = 0; kt < K; kt += 32) {
        __builtin_amdgcn_global_load_lds(
            (const __attribute__((address_space(1))) unsigned*)ga0,
            (__attribute__((address_space(3))) unsigned*)lA0, 16, 0, 0);
        __builtin_amdgcn_global_load_lds(
            (const __attribute__((address_space(1))) unsigned*)ga1,
            (__attribute__((address_space(3))) unsigned*)lA1, 16, 0, 0);
        __builtin_amdgcn_global_load_lds(
            (const __attribute__((address_space(1))) unsigned*)gb0,
            (__attribute__((address_space(3))) unsigned*)lB0, 16, 0, 0);
        __builtin_amdgcn_global_load_lds(
            (const __attribute__((address_space(1))) unsigned*)gb1,
            (__attribute__((address_space(3))) unsigned*)lB1, 16, 0, 0);
        ga0 += 32; ga1 += 32; gb0 += 32; gb1 += 32;
        __syncthreads();

        bf16x8 af[4], bfr[4];
#pragma unroll
        for (int i = 0; i < 4; i++) {
            af[i] = *(const bf16x8*)(As + aoff[i]);
            bfr[i] = *(const bf16x8*)(Bs + boff[i]);
        }
#pragma unroll
        for (int i = 0; i < 4; i++)
#pragma unroll
            for (int j = 0; j < 4; j++)
                acc[i][j] = __builtin_amdgcn_mfma_f32_16x16x32_bf16(af[i], bfr[j], acc[i][j], 0, 0, 0);
        __syncthreads();
    }

    // epilogue: C/D layout col=lane&15, row=q*4+reg  [m89/m91]; store bf16
#pragma unroll
    for (int i = 0; i < 4; i++) {
        int rbase = row0 + wm + i * 16 + q * 4;
        float pd[4];
#pragma unroll
        for (int r = 0; r < 4; r++)
            pd[r] = (scale && rbase + r < M) ? dinv[rbase + r] : 1.0f;
#pragma unroll
        for (int j = 0; j < 4; j++) {
            int gc = col0 + wn + j * 16 + ml;
#pragma unroll
            for (int r = 0; r < 4; r++) {
                int gr = rbase + r;
                if (gr < M) C[(size_t)gr * N + gc] = f2bf(pd[r] * acc[i][j][r]);
            }
        }
    }
}

// Layer-1 aggregate over UNSCALED g: h1 = relu(pd*(pd*g[d] + sum ps*g[s]) + b)
// g: [n][512] bf16 as uint2 (128/row); 128 thr/block; col+dinv via shfl bcast.
__global__ __launch_bounds__(128) void aggregate1(const uint2* __restrict__ g,
                                                  const int* __restrict__ row_start,
                                                  const int* __restrict__ deg,
                                                  const int* __restrict__ col_idx,
                                                  const float* __restrict__ dinv,
                                                  const float* __restrict__ bias,
                                                  uint2* __restrict__ out) {
    const int d = blockIdx.x, t = threadIdx.x;
    const int s0 = row_start[d], cnt = deg[d];
    const float pd = dinv[d];
    const size_t base = (size_t)d * 128 + t;

    uint2 us = g[base];
    float a0 = pd * bf_lo(us.x), a1 = pd * bf_hi(us.x);
    float a2 = pd * bf_lo(us.y), a3 = pd * bf_hi(us.y);  // self term (pd*g[d])

    int e = 0;
    for (; e + 8 <= cnt; e += 8) {
        int cv = col_idx[s0 + e + (t & 7)];
        float dv = dinv[cv];
        uint2 u[8];
        float ps[8];
#pragma unroll
        for (int j = 0; j < 8; j++) {
            int s = __shfl(cv, j);
            ps[j] = __shfl(dv, j);
            u[j] = g[(size_t)s * 128 + t];
        }
#pragma unroll
        for (int j = 0; j < 8; j++) {
            a0 = fmaf(ps[j], bf_lo(u[j].x), a0);
            a1 = fmaf(ps[j], bf_hi(u[j].x), a1);
            a2 = fmaf(ps[j], bf_lo(u[j].y), a2);
            a3 = fmaf(ps[j], bf_hi(u[j].y), a3);
        }
    }
    for (; e < cnt; e++) {
        int s = col_idx[s0 + e];
        float ps = dinv[s];
        uint2 u = g[(size_t)s * 128 + t];
        a0 = fmaf(ps, bf_lo(u.x), a0);
        a1 = fmaf(ps, bf_hi(u.x), a1);
        a2 = fmaf(ps, bf_lo(u.y), a2);
        a3 = fmaf(ps, bf_hi(u.y), a3);
    }
    float4 b = *(const float4*)(bias + t * 4);
    float o0 = fmaxf(fmaf(pd, a0, b.x), 0.0f);
    float o1 = fmaxf(fmaf(pd, a1, b.y), 0.0f);
    float o2 = fmaxf(fmaf(pd, a2, b.z), 0.0f);
    float o3 = fmaxf(fmaf(pd, a3, b.w), 0.0f);
    uint2 o;
    o.x = (uint_t)f2bf(o0) | ((uint_t)f2bf(o1) << 16);
    o.y = (uint_t)f2bf(o2) | ((uint_t)f2bf(o3) << 16);
    out[base] = o;
}

// Layer-2 aggregate over PRE-SCALED g2: out = relu(pd*(g[d]+sum g[s]) + b)
// g: [n][256] bf16 as uint2 (64/row); one wave per node.
__global__ __launch_bounds__(64) void aggregate2(const uint2* __restrict__ g,
                                                 const int* __restrict__ row_start,
                                                 const int* __restrict__ deg,
                                                 const int* __restrict__ col_idx,
                                                 const float* __restrict__ dinv,
                                                 const float* __restrict__ bias,
                                                 float* __restrict__ out) {
    const int d = blockIdx.x, t = threadIdx.x;
    const int s0 = row_start[d], cnt = deg[d];
    const float pd = dinv[d];
    const size_t base = (size_t)d * 64 + t;

    uint2 us = g[base];
    float a0 = bf_lo(us.x), a1 = bf_hi(us.x);
    float a2 = bf_lo(us.y), a3 = bf_hi(us.y);  // self term

    int e = 0;
    for (; e + 8 <= cnt; e += 8) {
        int cv = col_idx[s0 + e + (t & 7)];
        uint2 u[8];
#pragma unroll
        for (int j = 0; j < 8; j++) {
            int s = __shfl(cv, j);
            u[j] = g[(size_t)s * 64 + t];
        }
#pragma unroll
        for (int j = 0; j < 8; j++) {
            a0 += bf_lo(u[j].x); a1 += bf_hi(u[j].x);
            a2 += bf_lo(u[j].y); a3 += bf_hi(u[j].y);
        }
    }
    for (; e < cnt; e++) {
        uint2 u = g[(size_t)col_idx[s0 + e] * 64 + t];
        a0 += bf_lo(u.x); a1 += bf_hi(u.x);
        a2 += bf_lo(u.y); a3 += bf_hi(u.y);
    }
    float4 b = *(const float4*)(bias + t * 4);
    float4 o;
    o.x = fmaxf(fmaf(pd, a0, b.x), 0.0f);
    o.y = fmaxf(fmaf(pd, a1, b.y), 0.0f);
    o.z = fmaxf(fmaf(pd, a2, b.z), 0.0f);
    o.w = fmaxf(fmaf(pd, a3, b.w), 0.0f);
    *(float4*)(out + (size_t)d * 256 + t * 4) = o;
}

extern "C" void kernel_launch(void* const* d_in, const int* in_sizes, int n_in,
                              void* d_out, int out_size, void* d_ws, size_t ws_size,
                              hipStream_t stream) {
    const float* x  = (const float*)d_in[0];
    const int*   ei = (const int*)d_in[1];   // int32 on device
    const float* W1 = (const float*)d_in[2];
    const float* b1 = (const float*)d_in[3];
    const float* W2 = (const float*)d_in[4];
    const float* b2 = (const float*)d_in[5];
    float* out = (float*)d_out;

    const int FIN = 512, FH = 512, FOUT = 256;
    const int n = in_sizes[0] / FIN;  // 20000
    const int e = in_sizes[1] / 2;    // 160000
    const int* src = ei;
    const int* dst = ei + e;

    auto align_up = [](size_t v) { return (v + 255) & ~(size_t)255; };
    char* w = (char*)d_ws;
    int*      deg       = (int*)w;                         // deg[n] + counter adjacent
    int*      counter   = deg + n;
    w += align_up((size_t)(n + 1) * 4);
    float*    dinv      = (float*)w;    w += align_up((size_t)n * 4);
    int*      row_start = (int*)w;      w += align_up((size_t)n * 4);
    int*      fill_pos  = (int*)w;      w += align_up((size_t)n * 4);
    int*      col_idx   = (int*)w;      w += align_up((size_t)e * 4);
    ushort_t* xb        = (ushort_t*)w; w += align_up((size_t)n * FIN * 2);
    ushort_t* w1t       = (ushort_t*)w; w += align_up((size_t)FH * FIN * 2);
    ushort_t* w2t       = (ushort_t*)w; w += align_up((size_t)FOUT * FH * 2);
    ushort_t* g         = (ushort_t*)w; w += align_up((size_t)n * FH * 2);  // bf16, reused L2
    ushort_t* h1b       = (ushort_t*)w; w += align_up((size_t)n * FH * 2);

    const int nb_n = (n + 255) / 256;
    const int nb_e = (e + 255) / 256;
    const long xcount = (long)n * FIN;
    const int nb_conv = (int)((xcount / 4 + 255) / 256);

    hipMemsetAsync(deg, 0, (size_t)(n + 1) * 4, stream);  // deg + counter

    prep_fused<<<nb_e + nb_conv + 256 + 128, 256, 0, stream>>>(
        dst, deg, e, nb_e, x, xb, xcount, nb_conv, W1, w1t, W2, w2t);

    const int mb = (n + 127) / 128;
    // layer 1 GEMM (unscaled) + fused assign_ranges tail blocks
    {
        int gemm_blocks = (FH / 128) * mb;
        gemm_mfma<<<gemm_blocks + nb_n, 256, 0, stream>>>(
            xb, w1t, nullptr, g, n, FH, FIN, FH / 128, gemm_blocks, 0,
            deg, counter, row_start, fill_pos, dinv, n);
    }
    fill_csr<<<nb_e, 256, 0, stream>>>(src, dst, fill_pos, col_idx, e);
    aggregate1<<<n, 128, 0, stream>>>((const uint2*)g, row_start, deg, col_idx,
                                      dinv, b1, (uint2*)h1b);
    // layer 2 GEMM (scaled by dinv in epilogue), no tail blocks
    {
        int gemm_blocks = (FOUT / 128) * mb;
        gemm_mfma<<<gemm_blocks, 256, 0, stream>>>(
            h1b, w2t, dinv, g, n, FOUT, FH, FOUT / 128, gemm_blocks, 1,
            nullptr, nullptr, nullptr, nullptr, nullptr, 0);
    }
    aggregate2<<<n, 64, 0, stream>>>((const uint2*)g, row_start, deg, col_idx,
                                     dinv, b2, out);

    (void)ws_size; (void)n_in; (void)out_size;
}

// Round 6
// 193.310 us; speedup vs baseline: 2.4382x; 1.0909x over previous
//
#include <hip/hip_runtime.h>

// ---------------------------------------------------------------------------
// 2-layer GCN forward (PyG GCNConv) on MI355X, round 6.
//   out[d] = relu( p[d]*( sum_{s->d} p[s]*h[s] + p[d]*h[d] ) + b ),  h = x@W
// R6 changes vs R5:
//  - ELL adjacency (32 slots/node, overflow list for the ~never >32 case):
//    count+fill in ONE prep edge pass; assign_ranges/fill_csr dispatches gone.
//    gemm1 tail blocks now only compute dinv = rsqrt(deg+1).
//  - aggregates: branchless padded 8-batches (pad -> weight 0, row 0 = L2-hot);
//    no serial tail chains.
//  - GEMM: BK=64 K-loop (8 iters, half the barrier drains), 8-granule XOR
//    swizzle, same 16x16x32 bf16 MFMA 4x4 frags.
//  - 6 launches: memset, prep, gemm1(+dinv tail), agg1, gemm2, agg2.
// ---------------------------------------------------------------------------

typedef __bf16 bf16x8 __attribute__((ext_vector_type(8)));
typedef float floatx4 __attribute__((ext_vector_type(4)));
typedef unsigned short ushort_t;
typedef unsigned int uint_t;

#define MAXD 32

__device__ inline ushort_t f2bf(float f) {  // RNE fp32 -> bf16 bits
    unsigned u = __builtin_bit_cast(unsigned, f);
    unsigned r = (u + 0x7FFFu + ((u >> 16) & 1u)) >> 16;
    return (ushort_t)r;
}
__device__ inline float bf_lo(uint_t u) { return __builtin_bit_cast(float, u << 16); }
__device__ inline float bf_hi(uint_t u) { return __builtin_bit_cast(float, u & 0xFFFF0000u); }

// [K][N] fp32 -> [N][K] bf16, one 32x32 tile per block (256 thr)
__device__ inline void transpose_tile(const float* __restrict__ in,
                                      ushort_t* __restrict__ out,
                                      int K, int N, int k0, int n0,
                                      ushort_t (*tile)[33]) {
    int tx = threadIdx.x & 31, ty = threadIdx.x >> 5;  // ty 0..7
    for (int r = ty; r < 32; r += 8)
        tile[r][tx] = f2bf(in[(size_t)(k0 + r) * N + n0 + tx]);
    __syncthreads();
    for (int r = ty; r < 32; r += 8)
        out[(size_t)(n0 + r) * K + k0 + tx] = tile[tx][r];
}

// Fused preprocessing: edge pass (deg count + ELL fill) | x->bf16 | W1^T | W2^T
__global__ __launch_bounds__(256) void prep_fused(
    const int* __restrict__ src, const int* __restrict__ dst,
    int* __restrict__ deg, int* __restrict__ col_ell,
    int* __restrict__ ovf_cnt, int* __restrict__ ovf, int e, int nb_e,
    const float* __restrict__ x, ushort_t* __restrict__ xb, long xcount, int nb_conv,
    const float* __restrict__ W1, ushort_t* __restrict__ w1t,
    const float* __restrict__ W2, ushort_t* __restrict__ w2t) {
    __shared__ ushort_t tile[32][33];
    int b = blockIdx.x;
    if (b < nb_e) {
        int i = b * 256 + threadIdx.x;
        if (i < e) {
            int s = src[i], d = dst[i];
            int slot = atomicAdd(&deg[d], 1);
            if (slot < MAXD) {
                col_ell[d * MAXD + slot] = s;
            } else {
                int k = atomicAdd(ovf_cnt, 1);
                ovf[2 * k] = d;
                ovf[2 * k + 1] = s;
            }
        }
        return;
    }
    b -= nb_e;
    if (b < nb_conv) {
        long i = ((long)b * 256 + threadIdx.x) * 4;
        if (i < xcount) {
            float4 v = *(const float4*)(x + i);
            ushort4 o = make_ushort4(f2bf(v.x), f2bf(v.y), f2bf(v.z), f2bf(v.w));
            *(ushort4*)(xb + i) = o;
        }
        return;
    }
    b -= nb_conv;
    if (b < 256) {  // W1: K=512, N=512 -> 16x16 tiles
        transpose_tile(W1, w1t, 512, 512, (b >> 4) * 32, (b & 15) * 32, tile);
        return;
    }
    b -= 256;       // W2: K=512, N=256 -> 8x16 tiles
    transpose_tile(W2, w2t, 512, 256, (b >> 3) * 32, (b & 7) * 32, tile);
}

// GEMM (+ optional dinv tail blocks).
// C[r][c] = bf16( (scale?dinv[r]:1) * sum_k A[r][k]*BT[c][k] )
// A:[M][K], BT:[N][K] bf16. 128x128 tile, BK=64, 4 waves, 4x4 16x16x32 frags.
// LDS swizzle: position s (16B chunks, 8/row) holds global granule s^(r&7).
__global__ __launch_bounds__(256) void gemm_mfma(
    const ushort_t* __restrict__ A, const ushort_t* __restrict__ BT,
    const float* __restrict__ dinv, ushort_t* __restrict__ C,
    int M, int N, int K, int nbx, int gemm_blocks, int scale,
    const int* __restrict__ deg, float* __restrict__ dinv_out, int n) {
    __shared__ __align__(16) ushort_t As[8192];  // 128 rows x 64 k
    __shared__ __align__(16) ushort_t Bs[8192];

    if ((int)blockIdx.x >= gemm_blocks) {  // ---- dinv tail ----
        int i = ((int)blockIdx.x - gemm_blocks) * 256 + threadIdx.x;
        if (i < n) dinv_out[i] = 1.0f / sqrtf((float)(deg[i] + 1));
        return;
    }

    const int bx = (int)blockIdx.x % nbx, by = (int)blockIdx.x / nbx;
    const int tid = threadIdx.x;
    const int w = tid >> 6, lane = tid & 63;
    const int q = lane >> 4, ml = lane & 15;
    const int wm = (w >> 1) * 64, wn = (w & 1) * 64;
    const int row0 = by * 128, col0 = bx * 128;

    // staging: lane L covers row sub = L>>3, granule gsw = (L&7)^((L>>3)&7)
    const int rr = lane >> 3;                  // 0..7
    const int gsw = (lane & 7) ^ (rr & 7);     // global k-granule (x8 ushorts)
    const ushort_t* ga[4];
    const ushort_t* gb[4];
    ushort_t* la[4];
    ushort_t* lb[4];
#pragma unroll
    for (int rp = 0; rp < 4; rp++) {
        int r = rp * 32 + w * 8 + rr;
        int gra = min(row0 + r, M - 1);
        ga[rp] = A + (size_t)gra * K + gsw * 8;
        gb[rp] = BT + (size_t)(col0 + r) * K + gsw * 8;
        la[rp] = As + rp * 2048 + w * 512;  // wave-uniform; HW adds lane*16B
        lb[rp] = Bs + rp * 2048 + w * 512;
    }

    // fragment read offsets (ushort idx): row_loc*64 + ((g ^ (ml&7))*8)
    const int sel = ml & 7;
    int aoff[2][4], boff[2][4];
#pragma unroll
    for (int st = 0; st < 2; st++)
#pragma unroll
        for (int i = 0; i < 4; i++) {
            int g = q + st * 4;
            aoff[st][i] = (wm + i * 16 + ml) * 64 + ((g ^ sel) << 3);
            boff[st][i] = (wn + i * 16 + ml) * 64 + ((g ^ sel) << 3);
        }

    floatx4 acc[4][4];
#pragma unroll
    for (int i = 0; i < 4; i++)
#pragma unroll
        for (int j = 0; j < 4; j++) acc[i][j] = (floatx4)0.0f;

    for (int kt = 0; kt < K; kt += 64) {
#pragma unroll
        for (int rp = 0; rp < 4; rp++) {
            __builtin_amdgcn_global_load_lds(
                (const __attribute__((address_space(1))) unsigned*)ga[rp],
                (__attribute__((address_space(3))) unsigned*)la[rp], 16, 0, 0);
            __builtin_amdgcn_global_load_lds(
                (const __attribute__((address_space(1))) unsigned*)gb[rp],
                (__attribute__((address_space(3))) unsigned*)lb[rp], 16, 0, 0);
            ga[rp] += 64; gb[rp] += 64;
        }
        __syncthreads();
#pragma unroll
        for (int st = 0; st < 2; st++) {
            bf16x8 af[4], bfr[4];
#pragma unroll
            for (int i = 0; i < 4; i++) {
                af[i] = *(const bf16x8*)(As + aoff[st][i]);
                bfr[i] = *(const bf16x8*)(Bs + boff[st][i]);
            }
#pragma unroll
            for (int i = 0; i < 4; i++)
#pragma unroll
                for (int j = 0; j < 4; j++)
                    acc[i][j] = __builtin_amdgcn_mfma_f32_16x16x32_bf16(
                        af[i], bfr[j], acc[i][j], 0, 0, 0);
        }
        __syncthreads();
    }

    // epilogue: C/D layout col=lane&15, row=q*4+reg  [m89/m91]; store bf16
#pragma unroll
    for (int i = 0; i < 4; i++) {
        int rbase = row0 + wm + i * 16 + q * 4;
        float pd[4];
#pragma unroll
        for (int r = 0; r < 4; r++)
            pd[r] = (scale && rbase + r < M) ? dinv[rbase + r] : 1.0f;
#pragma unroll
        for (int j = 0; j < 4; j++) {
            int gc = col0 + wn + j * 16 + ml;
#pragma unroll
            for (int r = 0; r < 4; r++) {
                int gr = rbase + r;
                if (gr < M) C[(size_t)gr * N + gc] = f2bf(pd[r] * acc[i][j][r]);
            }
        }
    }
}

// Layer-1 aggregate over UNSCALED g: h1 = relu(pd*(pd*g[d] + sum ps*g[s]) + b)
// g: [n][512] bf16 as uint2; 128 thr/block. Branchless padded 8-batches:
// pad lanes get s=0 (L2-hot row), ps=0 -> zero contribution.
__global__ __launch_bounds__(128) void aggregate1(const uint2* __restrict__ g,
                                                  const int* __restrict__ deg,
                                                  const int* __restrict__ col_ell,
                                                  const int* __restrict__ ovf_cnt,
                                                  const int* __restrict__ ovf,
                                                  const float* __restrict__ dinv,
                                                  const float* __restrict__ bias,
                                                  uint2* __restrict__ out) {
    const int d = blockIdx.x, t = threadIdx.x;
    const int cnt = min(deg[d], MAXD);
    const float pd = dinv[d];
    const size_t base = (size_t)d * 128 + t;
    const int* cm = col_ell + (size_t)d * MAXD;

    uint2 us = g[base];
    float a0 = pd * bf_lo(us.x), a1 = pd * bf_hi(us.x);
    float a2 = pd * bf_lo(us.y), a3 = pd * bf_hi(us.y);  // self (pd*g[d])

    for (int e0 = 0; e0 < cnt; e0 += 8) {
        int idx = e0 + (t & 7);
        int inb = idx < cnt;
        int cv = inb ? cm[idx] : 0;
        float dv = inb ? dinv[cv] : 0.0f;
        uint2 u[8];
        float ps[8];
#pragma unroll
        for (int j = 0; j < 8; j++) {
            int s = __shfl(cv, j);
            ps[j] = __shfl(dv, j);
            u[j] = g[(size_t)s * 128 + t];
        }
#pragma unroll
        for (int j = 0; j < 8; j++) {
            a0 = fmaf(ps[j], bf_lo(u[j].x), a0);
            a1 = fmaf(ps[j], bf_hi(u[j].x), a1);
            a2 = fmaf(ps[j], bf_lo(u[j].y), a2);
            a3 = fmaf(ps[j], bf_hi(u[j].y), a3);
        }
    }
    int nov = *ovf_cnt;  // ~always 0
    for (int k = 0; k < nov; k++) {
        if (ovf[2 * k] == d) {
            int s = ovf[2 * k + 1];
            float ps = dinv[s];
            uint2 u = g[(size_t)s * 128 + t];
            a0 = fmaf(ps, bf_lo(u.x), a0);
            a1 = fmaf(ps, bf_hi(u.x), a1);
            a2 = fmaf(ps, bf_lo(u.y), a2);
            a3 = fmaf(ps, bf_hi(u.y), a3);
        }
    }
    float4 b = *(const float4*)(bias + t * 4);
    float o0 = fmaxf(fmaf(pd, a0, b.x), 0.0f);
    float o1 = fmaxf(fmaf(pd, a1, b.y), 0.0f);
    float o2 = fmaxf(fmaf(pd, a2, b.z), 0.0f);
    float o3 = fmaxf(fmaf(pd, a3, b.w), 0.0f);
    uint2 o;
    o.x = (uint_t)f2bf(o0) | ((uint_t)f2bf(o1) << 16);
    o.y = (uint_t)f2bf(o2) | ((uint_t)f2bf(o3) << 16);
    out[base] = o;
}

// Layer-2 aggregate over PRE-SCALED g2: out = relu(pd*(g[d]+sum g[s]) + b)
// g: [n][256] bf16 as uint2; one wave per node. Padded batches use weight 0/1.
__global__ __launch_bounds__(64) void aggregate2(const uint2* __restrict__ g,
                                                 const int* __restrict__ deg,
                                                 const int* __restrict__ col_ell,
                                                 const int* __restrict__ ovf_cnt,
                                                 const int* __restrict__ ovf,
                                                 const float* __restrict__ dinv,
                                                 const float* __restrict__ bias,
                                                 float* __restrict__ out) {
    const int d = blockIdx.x, t = threadIdx.x;
    const int cnt = min(deg[d], MAXD);
    const float pd = dinv[d];
    const size_t base = (size_t)d * 64 + t;
    const int* cm = col_ell + (size_t)d * MAXD;

    uint2 us = g[base];
    float a0 = bf_lo(us.x), a1 = bf_hi(us.x);
    float a2 = bf_lo(us.y), a3 = bf_hi(us.y);  // self term

    for (int e0 = 0; e0 < cnt; e0 += 8) {
        int idx = e0 + (t & 7);
        int inb = idx < cnt;
        int cv = inb ? cm[idx] : 0;
        float wv = inb ? 1.0f : 0.0f;
        uint2 u[8];
        float ws[8];
#pragma unroll
        for (int j = 0; j < 8; j++) {
            int s = __shfl(cv, j);
            ws[j] = __shfl(wv, j);
            u[j] = g[(size_t)s * 64 + t];
        }
#pragma unroll
        for (int j = 0; j < 8; j++) {
            a0 = fmaf(ws[j], bf_lo(u[j].x), a0);
            a1 = fmaf(ws[j], bf_hi(u[j].x), a1);
            a2 = fmaf(ws[j], bf_lo(u[j].y), a2);
            a3 = fmaf(ws[j], bf_hi(u[j].y), a3);
        }
    }
    int nov = *ovf_cnt;  // ~always 0
    for (int k = 0; k < nov; k++) {
        if (ovf[2 * k] == d) {
            uint2 u = g[(size_t)ovf[2 * k + 1] * 64 + t];
            a0 += bf_lo(u.x); a1 += bf_hi(u.x);
            a2 += bf_lo(u.y); a3 += bf_hi(u.y);
        }
    }
    float4 b = *(const float4*)(bias + t * 4);
    float4 o;
    o.x = fmaxf(fmaf(pd, a0, b.x), 0.0f);
    o.y = fmaxf(fmaf(pd, a1, b.y), 0.0f);
    o.z = fmaxf(fmaf(pd, a2, b.z), 0.0f);
    o.w = fmaxf(fmaf(pd, a3, b.w), 0.0f);
    *(float4*)(out + (size_t)d * 256 + t * 4) = o;
}

extern "C" void kernel_launch(void* const* d_in, const int* in_sizes, int n_in,
                              void* d_out, int out_size, void* d_ws, size_t ws_size,
                              hipStream_t stream) {
    const float* x  = (const float*)d_in[0];
    const int*   ei = (const int*)d_in[1];   // int32 on device
    const float* W1 = (const float*)d_in[2];
    const float* b1 = (const float*)d_in[3];
    const float* W2 = (const float*)d_in[4];
    const float* b2 = (const float*)d_in[5];
    float* out = (float*)d_out;

    const int FIN = 512, FH = 512, FOUT = 256;
    const int n = in_sizes[0] / FIN;  // 20000
    const int e = in_sizes[1] / 2;    // 160000
    const int* src = ei;
    const int* dst = ei + e;

    auto align_up = [](size_t v) { return (v + 255) & ~(size_t)255; };
    char* w = (char*)d_ws;
    int*      deg     = (int*)w;                 // deg[n] + ovf_cnt adjacent
    int*      ovf_cnt = deg + n;
    w += align_up((size_t)(n + 1) * 4);
    float*    dinv    = (float*)w;    w += align_up((size_t)n * 4);
    int*      col_ell = (int*)w;      w += align_up((size_t)n * MAXD * 4);
    int*      ovf     = (int*)w;      w += align_up((size_t)2048 * 4);
    ushort_t* xb      = (ushort_t*)w; w += align_up((size_t)n * FIN * 2);
    ushort_t* w1t     = (ushort_t*)w; w += align_up((size_t)FH * FIN * 2);
    ushort_t* w2t     = (ushort_t*)w; w += align_up((size_t)FOUT * FH * 2);
    ushort_t* g       = (ushort_t*)w; w += align_up((size_t)n * FH * 2);  // reused L2
    ushort_t* h1b     = (ushort_t*)w; w += align_up((size_t)n * FH * 2);

    const int nb_n = (n + 255) / 256;
    const int nb_e = (e + 255) / 256;
    const long xcount = (long)n * FIN;
    const int nb_conv = (int)((xcount / 4 + 255) / 256);

    hipMemsetAsync(deg, 0, (size_t)(n + 1) * 4, stream);  // deg + ovf_cnt

    prep_fused<<<nb_e + nb_conv + 256 + 128, 256, 0, stream>>>(
        src, dst, deg, col_ell, ovf_cnt, ovf, e, nb_e,
        x, xb, xcount, nb_conv, W1, w1t, W2, w2t);

    const int mb = (n + 127) / 128;
    // layer 1 GEMM (unscaled) + dinv tail blocks
    {
        int gemm_blocks = (FH / 128) * mb;
        gemm_mfma<<<gemm_blocks + nb_n, 256, 0, stream>>>(
            xb, w1t, nullptr, g, n, FH, FIN, FH / 128, gemm_blocks, 0,
            deg, dinv, n);
    }
    aggregate1<<<n, 128, 0, stream>>>((const uint2*)g, deg, col_ell, ovf_cnt,
                                      ovf, dinv, b1, (uint2*)h1b);
    // layer 2 GEMM (scaled by dinv in epilogue)
    {
        int gemm_blocks = (FOUT / 128) * mb;
        gemm_mfma<<<gemm_blocks, 256, 0, stream>>>(
            h1b, w2t, dinv, g, n, FOUT, FH, FOUT / 128, gemm_blocks, 1,
            nullptr, nullptr, 0);
    }
    aggregate2<<<n, 64, 0, stream>>>((const uint2*)g, deg, col_ell, ovf_cnt,
                                     ovf, dinv, b2, out);

    (void)ws_size; (void)n_in; (void)out_size;
}

// Round 7
// 190.953 us; speedup vs baseline: 2.4683x; 1.0123x over previous
//
#include <hip/hip_runtime.h>

// ---------------------------------------------------------------------------
// 2-layer GCN forward (PyG GCNConv) on MI355X, round 7.
//   out[d] = relu( p[d]*( sum_{s->d} p[s]*h[s] + p[d]*h[d] ) + b ),  h = x@W
// R7 changes vs R6:
//  - aggregates: ALL ELL cols (<=32) + their dinv loaded ONCE into lanes 0-31
//    before the feature loop; 8-batches use pure __shfl (no per-batch
//    col->dinv dependent-load chain). Bias loaded early.
//  - everything else unchanged (ELL, BK=64 gemm, 6 launches).
// Floor analysis: agg1/agg2 are L3-BW bound (~7 TB/s on 164/82 MB logical;
// uniform-random graph -> per-XCD reuse ~1.1x, XCD chunking can't help);
// prep is HBM-bound; harness fill+restores ~58 us of the timed window.
// ---------------------------------------------------------------------------

typedef __bf16 bf16x8 __attribute__((ext_vector_type(8)));
typedef float floatx4 __attribute__((ext_vector_type(4)));
typedef unsigned short ushort_t;
typedef unsigned int uint_t;

#define MAXD 32

__device__ inline ushort_t f2bf(float f) {  // RNE fp32 -> bf16 bits
    unsigned u = __builtin_bit_cast(unsigned, f);
    unsigned r = (u + 0x7FFFu + ((u >> 16) & 1u)) >> 16;
    return (ushort_t)r;
}
__device__ inline float bf_lo(uint_t u) { return __builtin_bit_cast(float, u << 16); }
__device__ inline float bf_hi(uint_t u) { return __builtin_bit_cast(float, u & 0xFFFF0000u); }

// [K][N] fp32 -> [N][K] bf16, one 32x32 tile per block (256 thr)
__device__ inline void transpose_tile(const float* __restrict__ in,
                                      ushort_t* __restrict__ out,
                                      int K, int N, int k0, int n0,
                                      ushort_t (*tile)[33]) {
    int tx = threadIdx.x & 31, ty = threadIdx.x >> 5;  // ty 0..7
    for (int r = ty; r < 32; r += 8)
        tile[r][tx] = f2bf(in[(size_t)(k0 + r) * N + n0 + tx]);
    __syncthreads();
    for (int r = ty; r < 32; r += 8)
        out[(size_t)(n0 + r) * K + k0 + tx] = tile[tx][r];
}

// Fused preprocessing: edge pass (deg count + ELL fill) | x->bf16 | W1^T | W2^T
__global__ __launch_bounds__(256) void prep_fused(
    const int* __restrict__ src, const int* __restrict__ dst,
    int* __restrict__ deg, int* __restrict__ col_ell,
    int* __restrict__ ovf_cnt, int* __restrict__ ovf, int e, int nb_e,
    const float* __restrict__ x, ushort_t* __restrict__ xb, long xcount, int nb_conv,
    const float* __restrict__ W1, ushort_t* __restrict__ w1t,
    const float* __restrict__ W2, ushort_t* __restrict__ w2t) {
    __shared__ ushort_t tile[32][33];
    int b = blockIdx.x;
    if (b < nb_e) {
        int i = b * 256 + threadIdx.x;
        if (i < e) {
            int s = src[i], d = dst[i];
            int slot = atomicAdd(&deg[d], 1);
            if (slot < MAXD) {
                col_ell[d * MAXD + slot] = s;
            } else {
                int k = atomicAdd(ovf_cnt, 1);
                ovf[2 * k] = d;
                ovf[2 * k + 1] = s;
            }
        }
        return;
    }
    b -= nb_e;
    if (b < nb_conv) {
        long i = ((long)b * 256 + threadIdx.x) * 4;
        if (i < xcount) {
            float4 v = *(const float4*)(x + i);
            ushort4 o = make_ushort4(f2bf(v.x), f2bf(v.y), f2bf(v.z), f2bf(v.w));
            *(ushort4*)(xb + i) = o;
        }
        return;
    }
    b -= nb_conv;
    if (b < 256) {  // W1: K=512, N=512 -> 16x16 tiles
        transpose_tile(W1, w1t, 512, 512, (b >> 4) * 32, (b & 15) * 32, tile);
        return;
    }
    b -= 256;       // W2: K=512, N=256 -> 8x16 tiles
    transpose_tile(W2, w2t, 512, 256, (b >> 3) * 32, (b & 7) * 32, tile);
}

// GEMM (+ optional dinv tail blocks).
// C[r][c] = bf16( (scale?dinv[r]:1) * sum_k A[r][k]*BT[c][k] )
// A:[M][K], BT:[N][K] bf16. 128x128 tile, BK=64, 4 waves, 4x4 16x16x32 frags.
// LDS swizzle: position s (16B chunks, 8/row) holds global granule s^(r&7).
__global__ __launch_bounds__(256) void gemm_mfma(
    const ushort_t* __restrict__ A, const ushort_t* __restrict__ BT,
    const float* __restrict__ dinv, ushort_t* __restrict__ C,
    int M, int N, int K, int nbx, int gemm_blocks, int scale,
    const int* __restrict__ deg, float* __restrict__ dinv_out, int n) {
    __shared__ __align__(16) ushort_t As[8192];  // 128 rows x 64 k
    __shared__ __align__(16) ushort_t Bs[8192];

    if ((int)blockIdx.x >= gemm_blocks) {  // ---- dinv tail ----
        int i = ((int)blockIdx.x - gemm_blocks) * 256 + threadIdx.x;
        if (i < n) dinv_out[i] = 1.0f / sqrtf((float)(deg[i] + 1));
        return;
    }

    const int bx = (int)blockIdx.x % nbx, by = (int)blockIdx.x / nbx;
    const int tid = threadIdx.x;
    const int w = tid >> 6, lane = tid & 63;
    const int q = lane >> 4, ml = lane & 15;
    const int wm = (w >> 1) * 64, wn = (w & 1) * 64;
    const int row0 = by * 128, col0 = bx * 128;

    // staging: lane L covers row sub = L>>3, granule gsw = (L&7)^((L>>3)&7)
    const int rr = lane >> 3;                  // 0..7
    const int gsw = (lane & 7) ^ (rr & 7);     // global k-granule (x8 ushorts)
    const ushort_t* ga[4];
    const ushort_t* gb[4];
    ushort_t* la[4];
    ushort_t* lb[4];
#pragma unroll
    for (int rp = 0; rp < 4; rp++) {
        int r = rp * 32 + w * 8 + rr;
        int gra = min(row0 + r, M - 1);
        ga[rp] = A + (size_t)gra * K + gsw * 8;
        gb[rp] = BT + (size_t)(col0 + r) * K + gsw * 8;
        la[rp] = As + rp * 2048 + w * 512;  // wave-uniform; HW adds lane*16B
        lb[rp] = Bs + rp * 2048 + w * 512;
    }

    // fragment read offsets (ushort idx): row_loc*64 + ((g ^ (ml&7))*8)
    const int sel = ml & 7;
    int aoff[2][4], boff[2][4];
#pragma unroll
    for (int st = 0; st < 2; st++)
#pragma unroll
        for (int i = 0; i < 4; i++) {
            int g = q + st * 4;
            aoff[st][i] = (wm + i * 16 + ml) * 64 + ((g ^ sel) << 3);
            boff[st][i] = (wn + i * 16 + ml) * 64 + ((g ^ sel) << 3);
        }

    floatx4 acc[4][4];
#pragma unroll
    for (int i = 0; i < 4; i++)
#pragma unroll
        for (int j = 0; j < 4; j++) acc[i][j] = (floatx4)0.0f;

    for (int kt = 0; kt < K; kt += 64) {
#pragma unroll
        for (int rp = 0; rp < 4; rp++) {
            __builtin_amdgcn_global_load_lds(
                (const __attribute__((address_space(1))) unsigned*)ga[rp],
                (__attribute__((address_space(3))) unsigned*)la[rp], 16, 0, 0);
            __builtin_amdgcn_global_load_lds(
                (const __attribute__((address_space(1))) unsigned*)gb[rp],
                (__attribute__((address_space(3))) unsigned*)lb[rp], 16, 0, 0);
            ga[rp] += 64; gb[rp] += 64;
        }
        __syncthreads();
#pragma unroll
        for (int st = 0; st < 2; st++) {
            bf16x8 af[4], bfr[4];
#pragma unroll
            for (int i = 0; i < 4; i++) {
                af[i] = *(const bf16x8*)(As + aoff[st][i]);
                bfr[i] = *(const bf16x8*)(Bs + boff[st][i]);
            }
#pragma unroll
            for (int i = 0; i < 4; i++)
#pragma unroll
                for (int j = 0; j < 4; j++)
                    acc[i][j] = __builtin_amdgcn_mfma_f32_16x16x32_bf16(
                        af[i], bfr[j], acc[i][j], 0, 0, 0);
        }
        __syncthreads();
    }

    // epilogue: C/D layout col=lane&15, row=q*4+reg  [m89/m91]; store bf16
#pragma unroll
    for (int i = 0; i < 4; i++) {
        int rbase = row0 + wm + i * 16 + q * 4;
        float pd[4];
#pragma unroll
        for (int r = 0; r < 4; r++)
            pd[r] = (scale && rbase + r < M) ? dinv[rbase + r] : 1.0f;
#pragma unroll
        for (int j = 0; j < 4; j++) {
            int gc = col0 + wn + j * 16 + ml;
#pragma unroll
            for (int r = 0; r < 4; r++) {
                int gr = rbase + r;
                if (gr < M) C[(size_t)gr * N + gc] = f2bf(pd[r] * acc[i][j][r]);
            }
        }
    }
}

// Layer-1 aggregate over UNSCALED g: h1 = relu(pd*(pd*g[d] + sum ps*g[s]) + b)
// g: [n][512] bf16 as uint2; 128 thr/block. All <=32 cols + dinv preloaded
// into lanes 0-31 of each wave; batches are pure shfl + row-gather.
__global__ __launch_bounds__(128) void aggregate1(const uint2* __restrict__ g,
                                                  const int* __restrict__ deg,
                                                  const int* __restrict__ col_ell,
                                                  const int* __restrict__ ovf_cnt,
                                                  const int* __restrict__ ovf,
                                                  const float* __restrict__ dinv,
                                                  const float* __restrict__ bias,
                                                  uint2* __restrict__ out) {
    const int d = blockIdx.x, t = threadIdx.x;
    const int cnt = min(deg[d], MAXD);
    const float pd = dinv[d];
    const size_t base = (size_t)d * 128 + t;
    const int* cm = col_ell + (size_t)d * MAXD;

    // preload ALL cols + dinv once (lanes 0..31 of each wave; pads -> 0)
    const int lane = t & 63;
    int cv = 0;
    float dv = 0.0f;
    if (lane < MAXD && lane < cnt) {
        cv = cm[lane];
        dv = dinv[cv];
    }
    float4 b = *(const float4*)(bias + t * 4);

    uint2 us = g[base];
    float a0 = pd * bf_lo(us.x), a1 = pd * bf_hi(us.x);
    float a2 = pd * bf_lo(us.y), a3 = pd * bf_hi(us.y);  // self (pd*g[d])

    for (int e0 = 0; e0 < cnt; e0 += 8) {
        uint2 u[8];
        float ps[8];
#pragma unroll
        for (int j = 0; j < 8; j++) {
            int s = __shfl(cv, e0 + j);
            ps[j] = __shfl(dv, e0 + j);
            u[j] = g[(size_t)s * 128 + t];
        }
#pragma unroll
        for (int j = 0; j < 8; j++) {
            a0 = fmaf(ps[j], bf_lo(u[j].x), a0);
            a1 = fmaf(ps[j], bf_hi(u[j].x), a1);
            a2 = fmaf(ps[j], bf_lo(u[j].y), a2);
            a3 = fmaf(ps[j], bf_hi(u[j].y), a3);
        }
    }
    int nov = *ovf_cnt;  // ~always 0
    for (int k = 0; k < nov; k++) {
        if (ovf[2 * k] == d) {
            int s = ovf[2 * k + 1];
            float ps = dinv[s];
            uint2 u = g[(size_t)s * 128 + t];
            a0 = fmaf(ps, bf_lo(u.x), a0);
            a1 = fmaf(ps, bf_hi(u.x), a1);
            a2 = fmaf(ps, bf_lo(u.y), a2);
            a3 = fmaf(ps, bf_hi(u.y), a3);
        }
    }
    float o0 = fmaxf(fmaf(pd, a0, b.x), 0.0f);
    float o1 = fmaxf(fmaf(pd, a1, b.y), 0.0f);
    float o2 = fmaxf(fmaf(pd, a2, b.z), 0.0f);
    float o3 = fmaxf(fmaf(pd, a3, b.w), 0.0f);
    uint2 o;
    o.x = (uint_t)f2bf(o0) | ((uint_t)f2bf(o1) << 16);
    o.y = (uint_t)f2bf(o2) | ((uint_t)f2bf(o3) << 16);
    out[base] = o;
}

// Layer-2 aggregate over PRE-SCALED g2: out = relu(pd*(g[d]+sum g[s]) + b)
// g: [n][256] bf16 as uint2; one wave per node; cols preloaded once.
__global__ __launch_bounds__(64) void aggregate2(const uint2* __restrict__ g,
                                                 const int* __restrict__ deg,
                                                 const int* __restrict__ col_ell,
                                                 const int* __restrict__ ovf_cnt,
                                                 const int* __restrict__ ovf,
                                                 const float* __restrict__ dinv,
                                                 const float* __restrict__ bias,
                                                 float* __restrict__ out) {
    const int d = blockIdx.x, t = threadIdx.x;
    const int cnt = min(deg[d], MAXD);
    const float pd = dinv[d];
    const size_t base = (size_t)d * 64 + t;
    const int* cm = col_ell + (size_t)d * MAXD;

    int cv = 0;
    float wv = 0.0f;
    if (t < MAXD && t < cnt) {
        cv = cm[t];
        wv = 1.0f;
    }
    float4 b = *(const float4*)(bias + t * 4);

    uint2 us = g[base];
    float a0 = bf_lo(us.x), a1 = bf_hi(us.x);
    float a2 = bf_lo(us.y), a3 = bf_hi(us.y);  // self term

    for (int e0 = 0; e0 < cnt; e0 += 8) {
        uint2 u[8];
        float ws[8];
#pragma unroll
        for (int j = 0; j < 8; j++) {
            int s = __shfl(cv, e0 + j);
            ws[j] = __shfl(wv, e0 + j);
            u[j] = g[(size_t)s * 64 + t];
        }
#pragma unroll
        for (int j = 0; j < 8; j++) {
            a0 = fmaf(ws[j], bf_lo(u[j].x), a0);
            a1 = fmaf(ws[j], bf_hi(u[j].x), a1);
            a2 = fmaf(ws[j], bf_lo(u[j].y), a2);
            a3 = fmaf(ws[j], bf_hi(u[j].y), a3);
        }
    }
    int nov = *ovf_cnt;  // ~always 0
    for (int k = 0; k < nov; k++) {
        if (ovf[2 * k] == d) {
            uint2 u = g[(size_t)ovf[2 * k + 1] * 64 + t];
            a0 += bf_lo(u.x); a1 += bf_hi(u.x);
            a2 += bf_lo(u.y); a3 += bf_hi(u.y);
        }
    }
    float4 o;
    o.x = fmaxf(fmaf(pd, a0, b.x), 0.0f);
    o.y = fmaxf(fmaf(pd, a1, b.y), 0.0f);
    o.z = fmaxf(fmaf(pd, a2, b.z), 0.0f);
    o.w = fmaxf(fmaf(pd, a3, b.w), 0.0f);
    *(float4*)(out + (size_t)d * 256 + t * 4) = o;
}

extern "C" void kernel_launch(void* const* d_in, const int* in_sizes, int n_in,
                              void* d_out, int out_size, void* d_ws, size_t ws_size,
                              hipStream_t stream) {
    const float* x  = (const float*)d_in[0];
    const int*   ei = (const int*)d_in[1];   // int32 on device
    const float* W1 = (const float*)d_in[2];
    const float* b1 = (const float*)d_in[3];
    const float* W2 = (const float*)d_in[4];
    const float* b2 = (const float*)d_in[5];
    float* out = (float*)d_out;

    const int FIN = 512, FH = 512, FOUT = 256;
    const int n = in_sizes[0] / FIN;  // 20000
    const int e = in_sizes[1] / 2;    // 160000
    const int* src = ei;
    const int* dst = ei + e;

    auto align_up = [](size_t v) { return (v + 255) & ~(size_t)255; };
    char* w = (char*)d_ws;
    int*      deg     = (int*)w;                 // deg[n] + ovf_cnt adjacent
    int*      ovf_cnt = deg + n;
    w += align_up((size_t)(n + 1) * 4);
    float*    dinv    = (float*)w;    w += align_up((size_t)n * 4);
    int*      col_ell = (int*)w;      w += align_up((size_t)n * MAXD * 4);
    int*      ovf     = (int*)w;      w += align_up((size_t)2048 * 4);
    ushort_t* xb      = (ushort_t*)w; w += align_up((size_t)n * FIN * 2);
    ushort_t* w1t     = (ushort_t*)w; w += align_up((size_t)FH * FIN * 2);
    ushort_t* w2t     = (ushort_t*)w; w += align_up((size_t)FOUT * FH * 2);
    ushort_t* g       = (ushort_t*)w; w += align_up((size_t)n * FH * 2);  // reused L2
    ushort_t* h1b     = (ushort_t*)w; w += align_up((size_t)n * FH * 2);

    const int nb_n = (n + 255) / 256;
    const int nb_e = (e + 255) / 256;
    const long xcount = (long)n * FIN;
    const int nb_conv = (int)((xcount / 4 + 255) / 256);

    hipMemsetAsync(deg, 0, (size_t)(n + 1) * 4, stream);  // deg + ovf_cnt

    prep_fused<<<nb_e + nb_conv + 256 + 128, 256, 0, stream>>>(
        src, dst, deg, col_ell, ovf_cnt, ovf, e, nb_e,
        x, xb, xcount, nb_conv, W1, w1t, W2, w2t);

    const int mb = (n + 127) / 128;
    // layer 1 GEMM (unscaled) + dinv tail blocks
    {
        int gemm_blocks = (FH / 128) * mb;
        gemm_mfma<<<gemm_blocks + nb_n, 256, 0, stream>>>(
            xb, w1t, nullptr, g, n, FH, FIN, FH / 128, gemm_blocks, 0,
            deg, dinv, n);
    }
    aggregate1<<<n, 128, 0, stream>>>((const uint2*)g, deg, col_ell, ovf_cnt,
                                      ovf, dinv, b1, (uint2*)h1b);
    // layer 2 GEMM (scaled by dinv in epilogue)
    {
        int gemm_blocks = (FOUT / 128) * mb;
        gemm_mfma<<<gemm_blocks, 256, 0, stream>>>(
            h1b, w2t, dinv, g, n, FOUT, FH, FOUT / 128, gemm_blocks, 1,
            nullptr, nullptr, 0);
    }
    aggregate2<<<n, 64, 0, stream>>>((const uint2*)g, deg, col_ell, ovf_cnt,
                                     ovf, dinv, b2, out);

    (void)ws_size; (void)n_in; (void)out_size;
}